// Round 1
// baseline (1066.145 us; speedup 1.0000x reference)
//
#include <hip/hip_runtime.h>

// Problem constants (DeformableConvBlock: B=8, C=64, H=W=128)
#define BB 8
#define CC 64      // hr/lr channels; deform conv channels
#define C2 128     // concat channels
#define HH 128
#define WW 128

// ---------------------------------------------------------------------------
// Repack weights [O][CiK] (CiK = Ci*9, row-major as given) -> [CiK][O]
// so the per-(ci,k) weight vector over output channels is contiguous
// => wave-uniform contiguous addresses => compiler merges into s_load_dwordx16.
// ---------------------------------------------------------------------------
__global__ void repack_w(const float* __restrict__ w, float* __restrict__ wt,
                         int O, int CiK) {
    int i = blockIdx.x * 256 + threadIdx.x;
    if (i >= O * CiK) return;
    int o = i / CiK, ck = i - o * CiK;
    wt[(size_t)ck * O + o] = w[i];
}

// ---------------------------------------------------------------------------
// Direct 3x3 conv, stride 1, pad 1. One thread = one output pixel for
// CO_TILE output channels (accumulators in VGPRs, weights via scalar loads).
// Block = 256 threads = 2 rows x 128 cols. blockIdx.x = b*64 + rowpair.
// CONCAT: channels [0, CIN/2) from inA, [CIN/2, CIN) from inB (axis-1 concat).
// ---------------------------------------------------------------------------
template <int CIN, int CO_TILE, bool LEAKY, bool CONCAT>
__global__ __launch_bounds__(256) void conv3x3_k(
    const float* __restrict__ inA, const float* __restrict__ inB,
    const float* __restrict__ wt,   // [CIN*9][cout_total]
    float* __restrict__ out, int cout_total)
{
    const int t = threadIdx.x;
    const int x = t & (WW - 1);
    const int y = ((blockIdx.x & 63) << 1) | (t >> 7);
    const int b = blockIdx.x >> 6;
    const int co_base = blockIdx.y * CO_TILE;

    float acc[CO_TILE];
#pragma unroll
    for (int i = 0; i < CO_TILE; ++i) acc[i] = 0.f;

    for (int ci = 0; ci < CIN; ++ci) {
        const float* src;
        if (CONCAT) {
            src = (ci < CIN / 2)
                      ? inA + ((size_t)(b * (CIN / 2) + ci)) * (HH * WW)
                      : inB + ((size_t)(b * (CIN / 2) + (ci - CIN / 2))) * (HH * WW);
        } else {
            src = inA + ((size_t)(b * CIN + ci)) * (HH * WW);
        }
#pragma unroll
        for (int ky = 0; ky < 3; ++ky) {
            const int yy = y + ky - 1;
            const bool vy = ((unsigned)yy < (unsigned)HH);
            const float* row = src + min(max(yy, 0), HH - 1) * WW;
#pragma unroll
            for (int kx = 0; kx < 3; ++kx) {
                const int xx = x + kx - 1;
                const bool v_ok = vy && ((unsigned)xx < (unsigned)WW);
                float v = row[min(max(xx, 0), WW - 1)];   // clamped => always safe
                v = v_ok ? v : 0.f;                       // zero-padding
                const float* wp =
                    wt + (size_t)(ci * 9 + ky * 3 + kx) * cout_total + co_base;
#pragma unroll
                for (int co = 0; co < CO_TILE; ++co)
                    acc[co] += v * wp[co];                // SGPR-operand v_fma
            }
        }
    }

#pragma unroll
    for (int co = 0; co < CO_TILE; ++co) {
        float r = acc[co];
        if (LEAKY) r = (r >= 0.f) ? r : 0.1f * r;
        out[(((size_t)(b * cout_total + co_base + co)) * HH + y) * WW + x] = r;
    }
}

// ---------------------------------------------------------------------------
// Deformable conv 3x3, stride 1, pad 1, 1 offset group, no bias.
// One thread = one output pixel, all 64 output channels in registers.
// Bilinear sample position/weights computed once per tap k, reused over c.
// ---------------------------------------------------------------------------
__global__ __launch_bounds__(256) void deform_conv_k(
    const float* __restrict__ xin,   // [B][C][H][W] (hr_features)
    const float* __restrict__ off,   // [B][18][H][W] (dy,dx interleaved per tap)
    const float* __restrict__ wt,    // [C*9][C]  ((c*9+k)*C + o)
    float* __restrict__ out)         // [B][C][H][W]
{
    const int t = threadIdx.x;
    const int x = t & (WW - 1);
    const int y = ((blockIdx.x & 63) << 1) | (t >> 7);
    const int b = blockIdx.x >> 6;

    float acc[CC];
#pragma unroll
    for (int i = 0; i < CC; ++i) acc[i] = 0.f;

    const float* xb = xin + (size_t)b * CC * HH * WW;
    const size_t offb = (size_t)b * 18 * HH * WW + (size_t)y * WW + x;

    for (int k = 0; k < 9; ++k) {
        const int ky = k / 3 - 1;
        const int kx = k % 3 - 1;
        const float dy = off[offb + (size_t)(2 * k) * (HH * WW)];
        const float dx = off[offb + (size_t)(2 * k + 1) * (HH * WW)];
        const float py = (float)(y + ky) + dy;
        const float px = (float)(x + kx) + dx;
        const float y0f = floorf(py), x0f = floorf(px);
        const float wy1 = py - y0f, wx1 = px - x0f;
        const float wy0 = 1.f - wy1, wx0 = 1.f - wx1;
        const int y0 = (int)y0f, x0 = (int)x0f;
        const int y1 = y0 + 1, x1 = x0 + 1;
        const bool vy0 = ((unsigned)y0 < (unsigned)HH);
        const bool vy1 = ((unsigned)y1 < (unsigned)HH);
        const bool vx0 = ((unsigned)x0 < (unsigned)WW);
        const bool vx1 = ((unsigned)x1 < (unsigned)WW);
        const float w00 = wy0 * wx0 * ((vy0 && vx0) ? 1.f : 0.f);
        const float w01 = wy0 * wx1 * ((vy0 && vx1) ? 1.f : 0.f);
        const float w10 = wy1 * wx0 * ((vy1 && vx0) ? 1.f : 0.f);
        const float w11 = wy1 * wx1 * ((vy1 && vx1) ? 1.f : 0.f);
        const int y0c = min(max(y0, 0), HH - 1), y1c = min(max(y1, 0), HH - 1);
        const int x0c = min(max(x0, 0), WW - 1), x1c = min(max(x1, 0), WW - 1);
        const int i00 = y0c * WW + x0c, i01 = y0c * WW + x1c;
        const int i10 = y1c * WW + x0c, i11 = y1c * WW + x1c;

        for (int c = 0; c < CC; ++c) {
            const float* p = xb + (size_t)c * (HH * WW);
            const float s = w00 * p[i00] + w01 * p[i01] + w10 * p[i10] + w11 * p[i11];
            const float* wp = wt + (size_t)(c * 9 + k) * CC;
#pragma unroll
            for (int o = 0; o < CC; ++o)
                acc[o] += s * wp[o];                       // SGPR-operand v_fma
        }
    }

#pragma unroll
    for (int o = 0; o < CC; ++o)
        out[(((size_t)(b * CC + o)) * HH + y) * WW + x] = acc[o];
}

// ---------------------------------------------------------------------------
// Launch: repack weights -> conv1 (concat+leaky) -> conv2 (offsets) -> deform.
// Workspace layout (floats):
//   est    : B*128*H*W       = 16,777,216
//   offset : B*18*H*W        =  2,359,296
//   wtE    : 128*9*128       =    147,456
//   wtO    : 128*9*18        =     20,736
//   wtD    : 64*9*64         =     36,864
// total ~77.4 MB  (assumed <= ws_size)
// ---------------------------------------------------------------------------
extern "C" void kernel_launch(void* const* d_in, const int* in_sizes, int n_in,
                              void* d_out, int out_size, void* d_ws, size_t ws_size,
                              hipStream_t stream) {
    const float* lr    = (const float*)d_in[0];
    const float* hr    = (const float*)d_in[1];
    const float* w_est = (const float*)d_in[2];   // [128][128][3][3]
    const float* w_off = (const float*)d_in[3];   // [18][128][3][3]
    const float* w_def = (const float*)d_in[4];   // [64][64][3][3]
    float* out = (float*)d_out;
    float* ws  = (float*)d_ws;

    float* est  = ws;
    float* offs = est  + (size_t)BB * C2 * HH * WW;
    float* wtE  = offs + (size_t)BB * 18 * HH * WW;
    float* wtO  = wtE  + (size_t)C2 * 9 * C2;
    float* wtD  = wtO  + (size_t)C2 * 9 * 18;

    // weight repacks (tiny)
    repack_w<<<(C2 * C2 * 9 + 255) / 256, 256, 0, stream>>>(w_est, wtE, C2, C2 * 9);
    repack_w<<<(18 * C2 * 9 + 255) / 256, 256, 0, stream>>>(w_off, wtO, 18, C2 * 9);
    repack_w<<<(CC * CC * 9 + 255) / 256, 256, 0, stream>>>(w_def, wtD, CC, CC * 9);

    // conv1: concat(lr,hr) -> est [B,128,H,W], leaky 0.1
    dim3 g1(BB * (HH / 2), C2 / 32);
    conv3x3_k<C2, 32, true, true><<<g1, 256, 0, stream>>>(lr, hr, wtE, est, C2);

    // conv2: est -> offset [B,18,H,W]
    dim3 g2(BB * (HH / 2), 1);
    conv3x3_k<C2, 18, false, false><<<g2, 256, 0, stream>>>(est, nullptr, wtO, offs, 18);

    // deform conv: hr + offset -> out [B,64,H,W]
    deform_conv_k<<<dim3(BB * (HH / 2)), 256, 0, stream>>>(hr, offs, wtD, out);
}

// Round 2
// 408.610 us; speedup vs baseline: 2.6092x; 2.6092x over previous
//
#include <hip/hip_runtime.h>

// DeformableConvBlock: B=8, C=64, H=W=128
#define BB 8
#define CC 64
#define C2 128
#define HH 128
#define WW 128
#define HW (HH * WW)

typedef __attribute__((ext_vector_type(8))) short bf16x8;
typedef __attribute__((ext_vector_type(4))) float f32x4;

__device__ inline ushort f2bf(float f) {
    union { float f; unsigned u; } v; v.f = f;
    unsigned r = v.u + 0x7fff + ((v.u >> 16) & 1);   // RNE
    return (ushort)(r >> 16);
}

// ---------------------------------------------------------------------------
// Pre-pass: concat(lr,hr) fp32 NCHW -> bf16 NHWC [b][y][x][128ci]
// One block per (b,y). LDS transpose for coalesced 16B stores.
// ---------------------------------------------------------------------------
__global__ __launch_bounds__(256) void to_nhwc_bf16(
    const float* __restrict__ lr, const float* __restrict__ hr,
    ushort* __restrict__ dst) {
    __shared__ ushort lt[HH][136];           // [x][ci], pad 136 (16B-aligned rows)
    const int t = threadIdx.x;
    const int b = blockIdx.x >> 7, y = blockIdx.x & 127;
    for (int ci0 = 0; ci0 < 128; ci0 += 2) {
        const int ci = ci0 + (t >> 7);
        const int x = t & 127;
        const float* s = (ci < 64) ? lr + ((size_t)(b * 64 + ci)) * HW
                                   : hr + ((size_t)(b * 64 + ci - 64)) * HW;
        lt[x][ci] = f2bf(s[y * WW + x]);
    }
    __syncthreads();
    ushort* db = dst + ((size_t)blockIdx.x) * WW * 128;
    for (int i = t; i < 128 * 16; i += 256) {
        const int px = i >> 4, q = i & 15;
        uint4 v = *(const uint4*)&lt[px][q * 8];
        *(uint4*)&db[(size_t)px * 128 + q * 8] = v;
    }
}

// ---------------------------------------------------------------------------
// Weight packs.  k-order: k = (cc*9 + tap)*32 + ci_sub  (cc = ci>>5)
// ---------------------------------------------------------------------------
__global__ void pack_wE(const float* __restrict__ w, ushort* __restrict__ o_) {
    int i = blockIdx.x * 256 + threadIdx.x;
    if (i >= 128 * 1152) return;
    int o = i / 1152, k = i % 1152;
    int cc = k / 288, rem = k % 288, tap = rem / 32, cs = rem % 32;
    int ci = cc * 32 + cs;
    o_[i] = f2bf(w[((size_t)o * 128 + ci) * 9 + tap]);
}
__global__ void pack_wO(const float* __restrict__ w, ushort* __restrict__ o_) {
    int i = blockIdx.x * 256 + threadIdx.x;
    if (i >= 32 * 1152) return;
    int o = i / 1152, k = i % 1152;
    int cc = k / 288, rem = k % 288, tap = rem / 32, cs = rem % 32;
    int ci = cc * 32 + cs;
    o_[i] = (o < 18) ? f2bf(w[((size_t)o * 128 + ci) * 9 + tap]) : (ushort)0;
}
__global__ void repack_w(const float* __restrict__ w, float* __restrict__ wt,
                         int O, int CiK) {
    int i = blockIdx.x * 256 + threadIdx.x;
    if (i >= O * CiK) return;
    int o = i / CiK, ck = i - o * CiK;
    wt[(size_t)ck * O + o] = w[i];
}

// ---------------------------------------------------------------------------
// Stage one ci-chunk (32 ci) of a 3-row input window into LDS [3][130][40]
// (pad 40 keeps ds_*_b128 16B-aligned and ~2-way conflict-free).
// ---------------------------------------------------------------------------
__device__ inline void stage_chunk(const ushort* __restrict__ nhwc_b, int y, int cc,
                                   ushort* __restrict__ lds) {
    for (int idx = threadIdx.x; idx < 3 * 130 * 4; idx += 256) {
        const int q  = idx & 3;
        const int px = (idx >> 2) % 130;
        const int r  = idx / 520;
        const int yy = y + r - 1;
        const int xx = px - 1;
        uint4 v = {0u, 0u, 0u, 0u};
        if ((unsigned)yy < (unsigned)HH && (unsigned)xx < (unsigned)WW)
            v = *(const uint4*)(nhwc_b + ((size_t)yy * WW + xx) * 128 + cc * 32 + q * 8);
        *(uint4*)(lds + (r * 130 + px) * 40 + q * 8) = v;
    }
}

// ---------------------------------------------------------------------------
// conv1: implicit-GEMM MFMA.  A = activations (M=128 px), B = wEb (N=128 co).
// Block = (b,y); 4 waves 2x2, wave tile 64px x 64co = 4x4 fragments.
// Epilogue: leaky(0.1) -> est bf16 NHWC.
// ---------------------------------------------------------------------------
__global__ __launch_bounds__(256) void conv1_mfma(
    const ushort* __restrict__ nhwc, const ushort* __restrict__ wEb,
    ushort* __restrict__ est) {
    __shared__ ushort lds[3 * 130 * 40];
    const int t = threadIdx.x, lane = t & 63, wid = t >> 6;
    const int wm = wid >> 1, wn = wid & 1;
    const int b = blockIdx.x >> 7, y = blockIdx.x & 127;
    const int l15 = lane & 15, lg = lane >> 4;
    const ushort* nb = nhwc + (size_t)(b * HH) * WW * 128;

    f32x4 acc[4][4] = {};
    for (int cc = 0; cc < 4; ++cc) {
        __syncthreads();
        stage_chunk(nb, y, cc, lds);
        __syncthreads();
#pragma unroll
        for (int tap = 0; tap < 9; ++tap) {
            const int ky = tap / 3, kx = tap % 3;
            bf16x8 a[4], w[4];
#pragma unroll
            for (int mt = 0; mt < 4; ++mt) {
                const int pxi = wm * 64 + mt * 16 + l15 + kx;  // (px+dx)+1 in [0,130)
                a[mt] = *(const bf16x8*)&lds[(ky * 130 + pxi) * 40 + lg * 8];
            }
            const int kb = (cc * 9 + tap) * 32 + lg * 8;
#pragma unroll
            for (int nt = 0; nt < 4; ++nt) {
                const int co = wn * 64 + nt * 16 + l15;
                w[nt] = *(const bf16x8*)&wEb[(size_t)co * 1152 + kb];
            }
#pragma unroll
            for (int mt = 0; mt < 4; ++mt)
#pragma unroll
                for (int nt = 0; nt < 4; ++nt)
                    acc[mt][nt] = __builtin_amdgcn_mfma_f32_16x16x32_bf16(
                        a[mt], w[nt], acc[mt][nt], 0, 0, 0);
        }
    }
    ushort* eb = est + ((size_t)blockIdx.x) * WW * 128;
#pragma unroll
    for (int mt = 0; mt < 4; ++mt)
#pragma unroll
        for (int nt = 0; nt < 4; ++nt)
#pragma unroll
            for (int j = 0; j < 4; ++j) {
                float r = acc[mt][nt][j];
                r = (r >= 0.f) ? r : 0.1f * r;
                const int px = wm * 64 + mt * 16 + lg * 4 + j;
                const int co = wn * 64 + nt * 16 + l15;
                eb[(size_t)px * 128 + co] = f2bf(r);
            }
}

// ---------------------------------------------------------------------------
// conv2: A = wOb (M=32 co, 18 valid), B = est (N=128 px).  D[cout][px] so
// fp32 stores are row-contiguous into offs [b][18][y][x].
// 4 waves split N: wave tile 32co x 32px = 2x2 fragments.
// ---------------------------------------------------------------------------
__global__ __launch_bounds__(256) void conv2_mfma(
    const ushort* __restrict__ est, const ushort* __restrict__ wOb,
    float* __restrict__ offs) {
    __shared__ ushort lds[3 * 130 * 40];
    const int t = threadIdx.x, lane = t & 63, wid = t >> 6;
    const int b = blockIdx.x >> 7, y = blockIdx.x & 127;
    const int l15 = lane & 15, lg = lane >> 4;
    const ushort* ebase = est + (size_t)(b * HH) * WW * 128;

    f32x4 acc[2][2] = {};
    for (int cc = 0; cc < 4; ++cc) {
        __syncthreads();
        stage_chunk(ebase, y, cc, lds);
        __syncthreads();
#pragma unroll
        for (int tap = 0; tap < 9; ++tap) {
            const int ky = tap / 3, kx = tap % 3;
            const int kb = (cc * 9 + tap) * 32 + lg * 8;
            bf16x8 a[2], bb[2];
#pragma unroll
            for (int mt = 0; mt < 2; ++mt)
                a[mt] = *(const bf16x8*)&wOb[(size_t)(mt * 16 + l15) * 1152 + kb];
#pragma unroll
            for (int nt = 0; nt < 2; ++nt) {
                const int pxi = wid * 32 + nt * 16 + l15 + kx;
                bb[nt] = *(const bf16x8*)&lds[(ky * 130 + pxi) * 40 + lg * 8];
            }
#pragma unroll
            for (int mt = 0; mt < 2; ++mt)
#pragma unroll
                for (int nt = 0; nt < 2; ++nt)
                    acc[mt][nt] = __builtin_amdgcn_mfma_f32_16x16x32_bf16(
                        a[mt], bb[nt], acc[mt][nt], 0, 0, 0);
        }
    }
    float* ob = offs + (size_t)b * 18 * HW + (size_t)y * WW;
#pragma unroll
    for (int mt = 0; mt < 2; ++mt)
#pragma unroll
        for (int nt = 0; nt < 2; ++nt)
#pragma unroll
            for (int j = 0; j < 4; ++j) {
                const int co = mt * 16 + lg * 4 + j;
                if (co < 18) {
                    const int px = wid * 32 + nt * 16 + l15;
                    ob[(size_t)co * HW + px] = acc[mt][nt][j];
                }
            }
}

// ---------------------------------------------------------------------------
// Deformable conv (unchanged from round 1 — fp32 VALU, passes refcheck).
// ---------------------------------------------------------------------------
__global__ __launch_bounds__(256) void deform_conv_k(
    const float* __restrict__ xin, const float* __restrict__ off,
    const float* __restrict__ wt, float* __restrict__ out) {
    const int t = threadIdx.x;
    const int x = t & (WW - 1);
    const int y = ((blockIdx.x & 63) << 1) | (t >> 7);
    const int b = blockIdx.x >> 6;

    float acc[CC];
#pragma unroll
    for (int i = 0; i < CC; ++i) acc[i] = 0.f;

    const float* xb = xin + (size_t)b * CC * HW;
    const size_t offb = (size_t)b * 18 * HW + (size_t)y * WW + x;

    for (int k = 0; k < 9; ++k) {
        const int ky = k / 3 - 1;
        const int kx = k % 3 - 1;
        const float dy = off[offb + (size_t)(2 * k) * HW];
        const float dx = off[offb + (size_t)(2 * k + 1) * HW];
        const float py = (float)(y + ky) + dy;
        const float px = (float)(x + kx) + dx;
        const float y0f = floorf(py), x0f = floorf(px);
        const float wy1 = py - y0f, wx1 = px - x0f;
        const float wy0 = 1.f - wy1, wx0 = 1.f - wx1;
        const int y0 = (int)y0f, x0 = (int)x0f;
        const int y1 = y0 + 1, x1 = x0 + 1;
        const bool vy0 = ((unsigned)y0 < (unsigned)HH);
        const bool vy1 = ((unsigned)y1 < (unsigned)HH);
        const bool vx0 = ((unsigned)x0 < (unsigned)WW);
        const bool vx1 = ((unsigned)x1 < (unsigned)WW);
        const float w00 = wy0 * wx0 * ((vy0 && vx0) ? 1.f : 0.f);
        const float w01 = wy0 * wx1 * ((vy0 && vx1) ? 1.f : 0.f);
        const float w10 = wy1 * wx0 * ((vy1 && vx0) ? 1.f : 0.f);
        const float w11 = wy1 * wx1 * ((vy1 && vx1) ? 1.f : 0.f);
        const int y0c = min(max(y0, 0), HH - 1), y1c = min(max(y1, 0), HH - 1);
        const int x0c = min(max(x0, 0), WW - 1), x1c = min(max(x1, 0), WW - 1);
        const int i00 = y0c * WW + x0c, i01 = y0c * WW + x1c;
        const int i10 = y1c * WW + x0c, i11 = y1c * WW + x1c;

        for (int c = 0; c < CC; ++c) {
            const float* p = xb + (size_t)c * HW;
            const float s = w00 * p[i00] + w01 * p[i01] + w10 * p[i10] + w11 * p[i11];
            const float* wp = wt + (size_t)(c * 9 + k) * CC;
#pragma unroll
            for (int o = 0; o < CC; ++o)
                acc[o] += s * wp[o];
        }
    }
#pragma unroll
    for (int o = 0; o < CC; ++o)
        out[(((size_t)(b * CC + o)) * HH + y) * WW + x] = acc[o];
}

// ---------------------------------------------------------------------------
// Workspace (bytes, 16B-aligned):
//   in_nhwc  bf16  33,554,432
//   est_nhwc bf16  33,554,432
//   offs     f32    9,437,184
//   wEb      bf16     294,912
//   wOb      bf16      73,728
//   wtD      f32      147,456
// total ~77.1 MB
// ---------------------------------------------------------------------------
extern "C" void kernel_launch(void* const* d_in, const int* in_sizes, int n_in,
                              void* d_out, int out_size, void* d_ws, size_t ws_size,
                              hipStream_t stream) {
    const float* lr    = (const float*)d_in[0];
    const float* hr    = (const float*)d_in[1];
    const float* w_est = (const float*)d_in[2];
    const float* w_off = (const float*)d_in[3];
    const float* w_def = (const float*)d_in[4];
    float* out = (float*)d_out;

    char* ws = (char*)d_ws;
    ushort* in_nhwc  = (ushort*)ws;                      ws += (size_t)BB * HH * WW * 128 * 2;
    ushort* est_nhwc = (ushort*)ws;                      ws += (size_t)BB * HH * WW * 128 * 2;
    float*  offs     = (float*)ws;                       ws += (size_t)BB * 18 * HW * 4;
    ushort* wEb      = (ushort*)ws;                      ws += (size_t)128 * 1152 * 2;
    ushort* wOb      = (ushort*)ws;                      ws += (size_t)32 * 1152 * 2;
    float*  wtD      = (float*)ws;

    pack_wE<<<(128 * 1152 + 255) / 256, 256, 0, stream>>>(w_est, wEb);
    pack_wO<<<(32 * 1152 + 255) / 256, 256, 0, stream>>>(w_off, wOb);
    repack_w<<<(CC * CC * 9 + 255) / 256, 256, 0, stream>>>(w_def, wtD, CC, CC * 9);

    to_nhwc_bf16<<<BB * HH, 256, 0, stream>>>(lr, hr, in_nhwc);

    conv1_mfma<<<BB * HH, 256, 0, stream>>>(in_nhwc, wEb, est_nhwc);
    conv2_mfma<<<BB * HH, 256, 0, stream>>>(est_nhwc, wOb, offs);

    deform_conv_k<<<dim3(BB * (HH / 2)), 256, 0, stream>>>(hr, offs, wtD, out);
}

// Round 3
// 311.147 us; speedup vs baseline: 3.4265x; 1.3132x over previous
//
#include <hip/hip_runtime.h>

// DeformableConvBlock: B=8, C=64, H=W=128
#define BB 8
#define CC 64
#define C2 128
#define HH 128
#define WW 128
#define HW (HH * WW)

typedef __attribute__((ext_vector_type(8))) short bf16x8;
typedef __attribute__((ext_vector_type(4))) float f32x4;

__device__ inline ushort f2bf(float f) {
    union { float f; unsigned u; } v; v.f = f;
    unsigned r = v.u + 0x7fff + ((v.u >> 16) & 1);   // RNE
    return (ushort)(r >> 16);
}
__device__ inline float bf2f(ushort u) {
    union { unsigned u; float f; } v; v.u = (unsigned)u << 16; return v.f;
}

// ---------------------------------------------------------------------------
// Pre-pass: concat(lr,hr) fp32 NCHW -> bf16 NHWC [b][y][x][128ci]
// ---------------------------------------------------------------------------
__global__ __launch_bounds__(256) void to_nhwc_bf16(
    const float* __restrict__ lr, const float* __restrict__ hr,
    ushort* __restrict__ dst) {
    __shared__ ushort lt[HH][136];
    const int t = threadIdx.x;
    const int b = blockIdx.x >> 7, y = blockIdx.x & 127;
    for (int ci0 = 0; ci0 < 128; ci0 += 2) {
        const int ci = ci0 + (t >> 7);
        const int x = t & 127;
        const float* s = (ci < 64) ? lr + ((size_t)(b * 64 + ci)) * HW
                                   : hr + ((size_t)(b * 64 + ci - 64)) * HW;
        lt[x][ci] = f2bf(s[y * WW + x]);
    }
    __syncthreads();
    ushort* db = dst + ((size_t)blockIdx.x) * WW * 128;
    for (int i = t; i < 128 * 16; i += 256) {
        const int px = i >> 4, q = i & 15;
        uint4 v = *(const uint4*)&lt[px][q * 8];
        *(uint4*)&db[(size_t)px * 128 + q * 8] = v;
    }
}

// ---------------------------------------------------------------------------
// Weight packs.
// conv weights: k = (cc*9 + tap)*32 + ci_sub   (cc = ci>>5)
// deform weights: [co][tap*64 + c]
// ---------------------------------------------------------------------------
__global__ void pack_wE(const float* __restrict__ w, ushort* __restrict__ o_) {
    int i = blockIdx.x * 256 + threadIdx.x;
    if (i >= 128 * 1152) return;
    int o = i / 1152, k = i % 1152;
    int cc = k / 288, rem = k % 288, tap = rem / 32, cs = rem % 32;
    int ci = cc * 32 + cs;
    o_[i] = f2bf(w[((size_t)o * 128 + ci) * 9 + tap]);
}
__global__ void pack_wO(const float* __restrict__ w, ushort* __restrict__ o_) {
    int i = blockIdx.x * 256 + threadIdx.x;
    if (i >= 32 * 1152) return;
    int o = i / 1152, k = i % 1152;
    int cc = k / 288, rem = k % 288, tap = rem / 32, cs = rem % 32;
    int ci = cc * 32 + cs;
    o_[i] = (o < 18) ? f2bf(w[((size_t)o * 128 + ci) * 9 + tap]) : (ushort)0;
}
__global__ void pack_wD(const float* __restrict__ w, ushort* __restrict__ o_) {
    int i = blockIdx.x * 256 + threadIdx.x;
    if (i >= 64 * 576) return;
    int o = i / 576, k = i % 576;
    int tap = k / 64, c = k % 64;
    o_[i] = f2bf(w[((size_t)o * 64 + c) * 9 + tap]);
}

// ---------------------------------------------------------------------------
// Stage one ci-chunk (32 ci) of a 3-row input window into LDS [3][130][40]
// ---------------------------------------------------------------------------
__device__ inline void stage_chunk(const ushort* __restrict__ nhwc_b, int y, int cc,
                                   ushort* __restrict__ lds) {
    for (int idx = threadIdx.x; idx < 3 * 130 * 4; idx += 256) {
        const int q  = idx & 3;
        const int px = (idx >> 2) % 130;
        const int r  = idx / 520;
        const int yy = y + r - 1;
        const int xx = px - 1;
        uint4 v = {0u, 0u, 0u, 0u};
        if ((unsigned)yy < (unsigned)HH && (unsigned)xx < (unsigned)WW)
            v = *(const uint4*)(nhwc_b + ((size_t)yy * WW + xx) * 128 + cc * 32 + q * 8);
        *(uint4*)(lds + (r * 130 + px) * 40 + q * 8) = v;
    }
}

// ---------------------------------------------------------------------------
// conv1: implicit-GEMM MFMA. est = leaky(conv(concat)) -> bf16 NHWC
// ---------------------------------------------------------------------------
__global__ __launch_bounds__(256) void conv1_mfma(
    const ushort* __restrict__ nhwc, const ushort* __restrict__ wEb,
    ushort* __restrict__ est) {
    __shared__ ushort lds[3 * 130 * 40];
    const int t = threadIdx.x, lane = t & 63, wid = t >> 6;
    const int wm = wid >> 1, wn = wid & 1;
    const int b = blockIdx.x >> 7, y = blockIdx.x & 127;
    const int l15 = lane & 15, lg = lane >> 4;
    const ushort* nb = nhwc + (size_t)(b * HH) * WW * 128;

    f32x4 acc[4][4] = {};
    for (int cc = 0; cc < 4; ++cc) {
        __syncthreads();
        stage_chunk(nb, y, cc, lds);
        __syncthreads();
#pragma unroll
        for (int tap = 0; tap < 9; ++tap) {
            const int ky = tap / 3, kx = tap % 3;
            bf16x8 a[4], w[4];
#pragma unroll
            for (int mt = 0; mt < 4; ++mt) {
                const int pxi = wm * 64 + mt * 16 + l15 + kx;
                a[mt] = *(const bf16x8*)&lds[(ky * 130 + pxi) * 40 + lg * 8];
            }
            const int kb = (cc * 9 + tap) * 32 + lg * 8;
#pragma unroll
            for (int nt = 0; nt < 4; ++nt) {
                const int co = wn * 64 + nt * 16 + l15;
                w[nt] = *(const bf16x8*)&wEb[(size_t)co * 1152 + kb];
            }
#pragma unroll
            for (int mt = 0; mt < 4; ++mt)
#pragma unroll
                for (int nt = 0; nt < 4; ++nt)
                    acc[mt][nt] = __builtin_amdgcn_mfma_f32_16x16x32_bf16(
                        a[mt], w[nt], acc[mt][nt], 0, 0, 0);
        }
    }
    ushort* eb = est + ((size_t)blockIdx.x) * WW * 128;
#pragma unroll
    for (int mt = 0; mt < 4; ++mt)
#pragma unroll
        for (int nt = 0; nt < 4; ++nt)
#pragma unroll
            for (int j = 0; j < 4; ++j) {
                float r = acc[mt][nt][j];
                r = (r >= 0.f) ? r : 0.1f * r;
                const int px = wm * 64 + mt * 16 + lg * 4 + j;
                const int co = wn * 64 + nt * 16 + l15;
                eb[(size_t)px * 128 + co] = f2bf(r);
            }
}

// ---------------------------------------------------------------------------
// conv2: offsets = conv(est).  A = wOb (32 rows, 18 valid), B = est pixels.
// ---------------------------------------------------------------------------
__global__ __launch_bounds__(256) void conv2_mfma(
    const ushort* __restrict__ est, const ushort* __restrict__ wOb,
    float* __restrict__ offs) {
    __shared__ ushort lds[3 * 130 * 40];
    const int t = threadIdx.x, lane = t & 63, wid = t >> 6;
    const int b = blockIdx.x >> 7, y = blockIdx.x & 127;
    const int l15 = lane & 15, lg = lane >> 4;
    const ushort* ebase = est + (size_t)(b * HH) * WW * 128;

    f32x4 acc[2][2] = {};
    for (int cc = 0; cc < 4; ++cc) {
        __syncthreads();
        stage_chunk(ebase, y, cc, lds);
        __syncthreads();
#pragma unroll
        for (int tap = 0; tap < 9; ++tap) {
            const int ky = tap / 3, kx = tap % 3;
            const int kb = (cc * 9 + tap) * 32 + lg * 8;
            bf16x8 a[2], bb[2];
#pragma unroll
            for (int mt = 0; mt < 2; ++mt)
                a[mt] = *(const bf16x8*)&wOb[(size_t)(mt * 16 + l15) * 1152 + kb];
#pragma unroll
            for (int nt = 0; nt < 2; ++nt) {
                const int pxi = wid * 32 + nt * 16 + l15 + kx;
                bb[nt] = *(const bf16x8*)&lds[(ky * 130 + pxi) * 40 + lg * 8];
            }
#pragma unroll
            for (int mt = 0; mt < 2; ++mt)
#pragma unroll
                for (int nt = 0; nt < 2; ++nt)
                    acc[mt][nt] = __builtin_amdgcn_mfma_f32_16x16x32_bf16(
                        a[mt], bb[nt], acc[mt][nt], 0, 0, 0);
        }
    }
    float* ob = offs + (size_t)b * 18 * HW + (size_t)y * WW;
#pragma unroll
    for (int mt = 0; mt < 2; ++mt)
#pragma unroll
        for (int nt = 0; nt < 2; ++nt)
#pragma unroll
            for (int j = 0; j < 4; ++j) {
                const int co = mt * 16 + lg * 4 + j;
                if (co < 18) {
                    const int px = wid * 32 + nt * 16 + l15;
                    ob[(size_t)co * HW + px] = acc[mt][nt][j];
                }
            }
}

// ---------------------------------------------------------------------------
// Deformable conv, MFMA version.
// Wave = 16 px x 64 co. B-frag (samples) is lane-local: lane l15 owns pixel
// l15, lane group lg owns channels [lg*8, lg*8+8). No LDS. A = packed weights
// [co][tap*64+c], 16B per-lane loads (L1/L2-hot).
// hr channels are read from the NHWC concat buffer at channel offset +64.
// ---------------------------------------------------------------------------
__global__ __launch_bounds__(256) void deform_mfma(
    const ushort* __restrict__ nhwc,   // [b][y][x][128]
    const float* __restrict__ offs,    // [b][18][H][W]
    const ushort* __restrict__ wD,     // [64][576]
    float* __restrict__ out) {         // [b][64][H][W]
    const int t = threadIdx.x, lane = t & 63, wid = t >> 6;
    const int l15 = lane & 15, lg = lane >> 4;
    const int bi = blockIdx.x;
    const int xh = bi & 1, y = (bi >> 1) & 127, b = bi >> 8;
    const int x = xh * 64 + wid * 16 + l15;

    f32x4 acc[4] = {};
    const ushort* nb = nhwc + (size_t)(b * HH) * WW * 128;
    const float* ob = offs + (size_t)b * 18 * HW + (size_t)y * WW + x;

#pragma unroll
    for (int k = 0; k < 9; ++k) {
        const int ky = k / 3 - 1, kx = k % 3 - 1;
        const float dy = ob[(size_t)(2 * k) * HW];
        const float dx = ob[(size_t)(2 * k + 1) * HW];
        const float py  = (float)(y + ky) + dy;
        const float pxf = (float)(x + kx) + dx;
        const float y0f = floorf(py), x0f = floorf(pxf);
        const float wy1 = py - y0f, wx1 = pxf - x0f;
        const float wy0 = 1.f - wy1, wx0 = 1.f - wx1;
        const int y0 = (int)y0f, x0 = (int)x0f;
        const int y1 = y0 + 1, x1 = x0 + 1;
        const bool vy0 = (unsigned)y0 < (unsigned)HH;
        const bool vy1 = (unsigned)y1 < (unsigned)HH;
        const bool vx0 = (unsigned)x0 < (unsigned)WW;
        const bool vx1 = (unsigned)x1 < (unsigned)WW;
        const float w00 = wy0 * wx0 * ((vy0 && vx0) ? 1.f : 0.f);
        const float w01 = wy0 * wx1 * ((vy0 && vx1) ? 1.f : 0.f);
        const float w10 = wy1 * wx0 * ((vy1 && vx0) ? 1.f : 0.f);
        const float w11 = wy1 * wx1 * ((vy1 && vx1) ? 1.f : 0.f);
        const int y0c = min(max(y0, 0), HH - 1), y1c = min(max(y1, 0), HH - 1);
        const int x0c = min(max(x0, 0), WW - 1), x1c = min(max(x1, 0), WW - 1);
        const size_t i00 = ((size_t)y0c * WW + x0c) * 128 + 64;
        const size_t i01 = ((size_t)y0c * WW + x1c) * 128 + 64;
        const size_t i10 = ((size_t)y1c * WW + x0c) * 128 + 64;
        const size_t i11 = ((size_t)y1c * WW + x1c) * 128 + 64;

#pragma unroll
        for (int h = 0; h < 2; ++h) {
            const int c0 = h * 32 + lg * 8;
            const bf16x8 v00 = *(const bf16x8*)&nb[i00 + c0];
            const bf16x8 v01 = *(const bf16x8*)&nb[i01 + c0];
            const bf16x8 v10 = *(const bf16x8*)&nb[i10 + c0];
            const bf16x8 v11 = *(const bf16x8*)&nb[i11 + c0];
            union { ushort s[8]; bf16x8 v; } bf;
#pragma unroll
            for (int j = 0; j < 8; ++j) {
                const float s = w00 * bf2f((ushort)v00[j]) + w01 * bf2f((ushort)v01[j])
                              + w10 * bf2f((ushort)v10[j]) + w11 * bf2f((ushort)v11[j]);
                bf.s[j] = f2bf(s);
            }
            const int kb = k * 64 + h * 32 + lg * 8;
#pragma unroll
            for (int mt = 0; mt < 4; ++mt) {
                const bf16x8 a = *(const bf16x8*)&wD[(size_t)(mt * 16 + l15) * 576 + kb];
                acc[mt] = __builtin_amdgcn_mfma_f32_16x16x32_bf16(a, bf.v, acc[mt], 0, 0, 0);
            }
        }
    }
#pragma unroll
    for (int mt = 0; mt < 4; ++mt)
#pragma unroll
        for (int j = 0; j < 4; ++j) {
            const int co = mt * 16 + lg * 4 + j;
            out[(((size_t)(b * CC + co)) * HH + y) * WW + x] = acc[mt][j];
        }
}

// ---------------------------------------------------------------------------
// Workspace:
//   in_nhwc  bf16  33,554,432
//   est_nhwc bf16  33,554,432
//   offs     f32    9,437,184
//   wEb      bf16     294,912
//   wOb      bf16      73,728
//   wDb      bf16      73,728
// total ~77 MB
// ---------------------------------------------------------------------------
extern "C" void kernel_launch(void* const* d_in, const int* in_sizes, int n_in,
                              void* d_out, int out_size, void* d_ws, size_t ws_size,
                              hipStream_t stream) {
    const float* lr    = (const float*)d_in[0];
    const float* hr    = (const float*)d_in[1];
    const float* w_est = (const float*)d_in[2];
    const float* w_off = (const float*)d_in[3];
    const float* w_def = (const float*)d_in[4];
    float* out = (float*)d_out;

    char* ws = (char*)d_ws;
    ushort* in_nhwc  = (ushort*)ws;   ws += (size_t)BB * HH * WW * 128 * 2;
    ushort* est_nhwc = (ushort*)ws;   ws += (size_t)BB * HH * WW * 128 * 2;
    float*  offs     = (float*)ws;    ws += (size_t)BB * 18 * HW * 4;
    ushort* wEb      = (ushort*)ws;   ws += (size_t)128 * 1152 * 2;
    ushort* wOb      = (ushort*)ws;   ws += (size_t)32 * 1152 * 2;
    ushort* wDb      = (ushort*)ws;

    pack_wE<<<(128 * 1152 + 255) / 256, 256, 0, stream>>>(w_est, wEb);
    pack_wO<<<(32 * 1152 + 255) / 256, 256, 0, stream>>>(w_off, wOb);
    pack_wD<<<(64 * 576 + 255) / 256, 256, 0, stream>>>(w_def, wDb);

    to_nhwc_bf16<<<BB * HH, 256, 0, stream>>>(lr, hr, in_nhwc);

    conv1_mfma<<<BB * HH, 256, 0, stream>>>(in_nhwc, wEb, est_nhwc);
    conv2_mfma<<<BB * HH, 256, 0, stream>>>(est_nhwc, wOb, offs);

    deform_mfma<<<BB * HH * 2, 256, 0, stream>>>(in_nhwc, offs, wDb, out);
}

// Round 4
// 310.090 us; speedup vs baseline: 3.4382x; 1.0034x over previous
//
#include <hip/hip_runtime.h>

// DeformableConvBlock: B=8, C=64, H=W=128
#define BB 8
#define CC 64
#define C2 128
#define HH 128
#define WW 128
#define HW (HH * WW)

typedef __attribute__((ext_vector_type(8))) short bf16x8;
typedef __attribute__((ext_vector_type(4))) float f32x4;

__device__ inline ushort f2bf(float f) {
    union { float f; unsigned u; } v; v.f = f;
    unsigned r = v.u + 0x7fff + ((v.u >> 16) & 1);   // RNE
    return (ushort)(r >> 16);
}
__device__ inline float bf2f(ushort u) {
    union { unsigned u; float f; } v; v.u = (unsigned)u << 16; return v.f;
}

// ---------------------------------------------------------------------------
// Pre-pass: concat(lr,hr) fp32 NCHW -> bf16 NHWC [b][y][x][128ci]
// ---------------------------------------------------------------------------
__global__ __launch_bounds__(256) void to_nhwc_bf16(
    const float* __restrict__ lr, const float* __restrict__ hr,
    ushort* __restrict__ dst) {
    __shared__ ushort lt[HH][136];
    const int t = threadIdx.x;
    const int b = blockIdx.x >> 7, y = blockIdx.x & 127;
    for (int ci0 = 0; ci0 < 128; ci0 += 2) {
        const int ci = ci0 + (t >> 7);
        const int x = t & 127;
        const float* s = (ci < 64) ? lr + ((size_t)(b * 64 + ci)) * HW
                                   : hr + ((size_t)(b * 64 + ci - 64)) * HW;
        lt[x][ci] = f2bf(s[y * WW + x]);
    }
    __syncthreads();
    ushort* db = dst + ((size_t)blockIdx.x) * WW * 128;
    for (int i = t; i < 128 * 16; i += 256) {
        const int px = i >> 4, q = i & 15;
        uint4 v = *(const uint4*)&lt[px][q * 8];
        *(uint4*)&db[(size_t)px * 128 + q * 8] = v;
    }
}

// ---------------------------------------------------------------------------
// Weight packs.
// conv weights: k = (cc*9 + tap)*32 + ci_sub   (cc = ci>>5)
// deform weights: [co][tap*64 + c]
// ---------------------------------------------------------------------------
__global__ void pack_wE(const float* __restrict__ w, ushort* __restrict__ o_) {
    int i = blockIdx.x * 256 + threadIdx.x;
    if (i >= 128 * 1152) return;
    int o = i / 1152, k = i % 1152;
    int cc = k / 288, rem = k % 288, tap = rem / 32, cs = rem % 32;
    int ci = cc * 32 + cs;
    o_[i] = f2bf(w[((size_t)o * 128 + ci) * 9 + tap]);
}
__global__ void pack_wO(const float* __restrict__ w, ushort* __restrict__ o_) {
    int i = blockIdx.x * 256 + threadIdx.x;
    if (i >= 32 * 1152) return;
    int o = i / 1152, k = i % 1152;
    int cc = k / 288, rem = k % 288, tap = rem / 32, cs = rem % 32;
    int ci = cc * 32 + cs;
    o_[i] = (o < 18) ? f2bf(w[((size_t)o * 128 + ci) * 9 + tap]) : (ushort)0;
}
__global__ void pack_wD(const float* __restrict__ w, ushort* __restrict__ o_) {
    int i = blockIdx.x * 256 + threadIdx.x;
    if (i >= 64 * 576) return;
    int o = i / 576, k = i % 576;
    int tap = k / 64, c = k % 64;
    o_[i] = f2bf(w[((size_t)o * 64 + c) * 9 + tap]);
}

// ---------------------------------------------------------------------------
// Stage one ci-chunk (32 ci) of a 3-row input window into LDS [3][130][40]
// ---------------------------------------------------------------------------
__device__ inline void stage_chunk(const ushort* __restrict__ nhwc_b, int y, int cc,
                                   ushort* __restrict__ lds) {
    for (int idx = threadIdx.x; idx < 3 * 130 * 4; idx += 256) {
        const int q  = idx & 3;
        const int px = (idx >> 2) % 130;
        const int r  = idx / 520;
        const int yy = y + r - 1;
        const int xx = px - 1;
        uint4 v = {0u, 0u, 0u, 0u};
        if ((unsigned)yy < (unsigned)HH && (unsigned)xx < (unsigned)WW)
            v = *(const uint4*)(nhwc_b + ((size_t)yy * WW + xx) * 128 + cc * 32 + q * 8);
        *(uint4*)(lds + (r * 130 + px) * 40 + q * 8) = v;
    }
}

// ---------------------------------------------------------------------------
// conv1: implicit-GEMM MFMA. est = leaky(conv(concat)) -> bf16 NHWC
// ---------------------------------------------------------------------------
__global__ __launch_bounds__(256) void conv1_mfma(
    const ushort* __restrict__ nhwc, const ushort* __restrict__ wEb,
    ushort* __restrict__ est) {
    __shared__ ushort lds[3 * 130 * 40];
    const int t = threadIdx.x, lane = t & 63, wid = t >> 6;
    const int wm = wid >> 1, wn = wid & 1;
    const int b = blockIdx.x >> 7, y = blockIdx.x & 127;
    const int l15 = lane & 15, lg = lane >> 4;
    const ushort* nb = nhwc + (size_t)(b * HH) * WW * 128;

    f32x4 acc[4][4] = {};
    for (int cc = 0; cc < 4; ++cc) {
        __syncthreads();
        stage_chunk(nb, y, cc, lds);
        __syncthreads();
#pragma unroll
        for (int tap = 0; tap < 9; ++tap) {
            const int ky = tap / 3, kx = tap % 3;
            bf16x8 a[4], w[4];
#pragma unroll
            for (int mt = 0; mt < 4; ++mt) {
                const int pxi = wm * 64 + mt * 16 + l15 + kx;
                a[mt] = *(const bf16x8*)&lds[(ky * 130 + pxi) * 40 + lg * 8];
            }
            const int kb = (cc * 9 + tap) * 32 + lg * 8;
#pragma unroll
            for (int nt = 0; nt < 4; ++nt) {
                const int co = wn * 64 + nt * 16 + l15;
                w[nt] = *(const bf16x8*)&wEb[(size_t)co * 1152 + kb];
            }
#pragma unroll
            for (int mt = 0; mt < 4; ++mt)
#pragma unroll
                for (int nt = 0; nt < 4; ++nt)
                    acc[mt][nt] = __builtin_amdgcn_mfma_f32_16x16x32_bf16(
                        a[mt], w[nt], acc[mt][nt], 0, 0, 0);
        }
    }
    ushort* eb = est + ((size_t)blockIdx.x) * WW * 128;
#pragma unroll
    for (int mt = 0; mt < 4; ++mt)
#pragma unroll
        for (int nt = 0; nt < 4; ++nt)
#pragma unroll
            for (int j = 0; j < 4; ++j) {
                float r = acc[mt][nt][j];
                r = (r >= 0.f) ? r : 0.1f * r;
                const int px = wm * 64 + mt * 16 + lg * 4 + j;
                const int co = wn * 64 + nt * 16 + l15;
                eb[(size_t)px * 128 + co] = f2bf(r);
            }
}

// ---------------------------------------------------------------------------
// conv2: offsets = conv(est).  A = wOb (32 rows, 18 valid), B = est pixels.
// ---------------------------------------------------------------------------
__global__ __launch_bounds__(256) void conv2_mfma(
    const ushort* __restrict__ est, const ushort* __restrict__ wOb,
    float* __restrict__ offs) {
    __shared__ ushort lds[3 * 130 * 40];
    const int t = threadIdx.x, lane = t & 63, wid = t >> 6;
    const int b = blockIdx.x >> 7, y = blockIdx.x & 127;
    const int l15 = lane & 15, lg = lane >> 4;
    const ushort* ebase = est + (size_t)(b * HH) * WW * 128;

    f32x4 acc[2][2] = {};
    for (int cc = 0; cc < 4; ++cc) {
        __syncthreads();
        stage_chunk(ebase, y, cc, lds);
        __syncthreads();
#pragma unroll
        for (int tap = 0; tap < 9; ++tap) {
            const int ky = tap / 3, kx = tap % 3;
            const int kb = (cc * 9 + tap) * 32 + lg * 8;
            bf16x8 a[2], bb[2];
#pragma unroll
            for (int mt = 0; mt < 2; ++mt)
                a[mt] = *(const bf16x8*)&wOb[(size_t)(mt * 16 + l15) * 1152 + kb];
#pragma unroll
            for (int nt = 0; nt < 2; ++nt) {
                const int pxi = wid * 32 + nt * 16 + l15 + kx;
                bb[nt] = *(const bf16x8*)&lds[(ky * 130 + pxi) * 40 + lg * 8];
            }
#pragma unroll
            for (int mt = 0; mt < 2; ++mt)
#pragma unroll
                for (int nt = 0; nt < 2; ++nt)
                    acc[mt][nt] = __builtin_amdgcn_mfma_f32_16x16x32_bf16(
                        a[mt], bb[nt], acc[mt][nt], 0, 0, 0);
        }
    }
    float* ob = offs + (size_t)b * 18 * HW + (size_t)y * WW;
#pragma unroll
    for (int mt = 0; mt < 2; ++mt)
#pragma unroll
        for (int nt = 0; nt < 2; ++nt)
#pragma unroll
            for (int j = 0; j < 4; ++j) {
                const int co = mt * 16 + lg * 4 + j;
                if (co < 18) {
                    const int px = wid * 32 + nt * 16 + l15;
                    ob[(size_t)co * HW + px] = acc[mt][nt][j];
                }
            }
}

// ---------------------------------------------------------------------------
// Deformable conv, MFMA + 1-tap-deep software pipeline.
// Wave = 16 px x 64 co; B-frag (samples) fully lane-local.
// Per tap k: issue gathers for k+1 (ping-pong regs) -> load A-frags for k
// (hidden under blend VALU) -> blend k -> 8 MFMAs.
// ---------------------------------------------------------------------------
__device__ inline void def_coords(const ushort* __restrict__ nb, int y, int x,
                                  int k, float dy, float dx, int chan_base,
                                  float* __restrict__ w,
                                  const ushort** __restrict__ p) {
    const int ky = k / 3 - 1, kx = k % 3 - 1;
    const float py  = (float)(y + ky) + dy;
    const float pxf = (float)(x + kx) + dx;
    const float y0f = floorf(py), x0f = floorf(pxf);
    const float wy1 = py - y0f, wx1 = pxf - x0f;
    const float wy0 = 1.f - wy1, wx0 = 1.f - wx1;
    const int y0 = (int)y0f, x0 = (int)x0f;
    const int y1 = y0 + 1, x1 = x0 + 1;
    const bool vy0 = (unsigned)y0 < (unsigned)HH;
    const bool vy1 = (unsigned)y1 < (unsigned)HH;
    const bool vx0 = (unsigned)x0 < (unsigned)WW;
    const bool vx1 = (unsigned)x1 < (unsigned)WW;
    w[0] = wy0 * wx0 * ((vy0 && vx0) ? 1.f : 0.f);
    w[1] = wy0 * wx1 * ((vy0 && vx1) ? 1.f : 0.f);
    w[2] = wy1 * wx0 * ((vy1 && vx0) ? 1.f : 0.f);
    w[3] = wy1 * wx1 * ((vy1 && vx1) ? 1.f : 0.f);
    const int y0c = min(max(y0, 0), HH - 1), y1c = min(max(y1, 0), HH - 1);
    const int x0c = min(max(x0, 0), WW - 1), x1c = min(max(x1, 0), WW - 1);
    p[0] = nb + ((size_t)y0c * WW + x0c) * 128 + chan_base;
    p[1] = nb + ((size_t)y0c * WW + x1c) * 128 + chan_base;
    p[2] = nb + ((size_t)y1c * WW + x0c) * 128 + chan_base;
    p[3] = nb + ((size_t)y1c * WW + x1c) * 128 + chan_base;
}

__global__ __launch_bounds__(256) void deform_mfma(
    const ushort* __restrict__ nhwc,   // [b][y][x][128]
    const float* __restrict__ offs,    // [b][18][H][W]
    const ushort* __restrict__ wD,     // [64][576]
    float* __restrict__ out) {         // [b][64][H][W]
    const int t = threadIdx.x, lane = t & 63, wid = t >> 6;
    const int l15 = lane & 15, lg = lane >> 4;
    const int bi = blockIdx.x;
    const int xh = bi & 1, y = (bi >> 1) & 127, b = bi >> 8;
    const int x = xh * 64 + wid * 16 + l15;

    const ushort* nb = nhwc + (size_t)(b * HH) * WW * 128;
    const float* ob = offs + (size_t)b * 18 * HW + (size_t)y * WW + x;
    const int cb = 64 + lg * 8;   // hr channels live at +64 in the concat buf

    // preload all 18 offset scalars (one wait, off the per-tap path)
    float dyv[9], dxv[9];
#pragma unroll
    for (int k = 0; k < 9; ++k) {
        dyv[k] = ob[(size_t)(2 * k) * HW];
        dxv[k] = ob[(size_t)(2 * k + 1) * HW];
    }

    float wcur[4], wnxt[4];
    bf16x8 gcur[8], gnxt[8];

    {   // prologue: issue tap-0 gathers
        const ushort* p[4];
        def_coords(nb, y, x, 0, dyv[0], dxv[0], cb, wcur, p);
#pragma unroll
        for (int c = 0; c < 4; ++c) {
            gcur[c]     = *(const bf16x8*)(p[c]);        // h=0: c in [lg*8, lg*8+8)
            gcur[4 + c] = *(const bf16x8*)(p[c] + 32);   // h=1: +32 channels
        }
    }

    f32x4 acc[4] = {};
#pragma unroll
    for (int k = 0; k < 9; ++k) {
        // 1) issue next tap's gathers (stay in flight across this tap's compute)
        if (k < 8) {
            const ushort* p[4];
            def_coords(nb, y, x, k + 1, dyv[k + 1], dxv[k + 1], cb, wnxt, p);
#pragma unroll
            for (int c = 0; c < 4; ++c) {
                gnxt[c]     = *(const bf16x8*)(p[c]);
                gnxt[4 + c] = *(const bf16x8*)(p[c] + 32);
            }
        }
        // 2) A-fragment loads for this tap (hidden under the blend VALU)
        bf16x8 afr[2][4];
#pragma unroll
        for (int h = 0; h < 2; ++h)
#pragma unroll
            for (int mt = 0; mt < 4; ++mt)
                afr[h][mt] = *(const bf16x8*)&wD[(size_t)(mt * 16 + l15) * 576
                                                + k * 64 + h * 32 + lg * 8];
        // 3) blend this tap's (already resident) gathers, 4) MFMA
#pragma unroll
        for (int h = 0; h < 2; ++h) {
            union { ushort s[8]; bf16x8 v; } bf;
#pragma unroll
            for (int j = 0; j < 8; ++j) {
                const float s = wcur[0] * bf2f((ushort)gcur[h * 4 + 0][j])
                              + wcur[1] * bf2f((ushort)gcur[h * 4 + 1][j])
                              + wcur[2] * bf2f((ushort)gcur[h * 4 + 2][j])
                              + wcur[3] * bf2f((ushort)gcur[h * 4 + 3][j]);
                bf.s[j] = f2bf(s);
            }
#pragma unroll
            for (int mt = 0; mt < 4; ++mt)
                acc[mt] = __builtin_amdgcn_mfma_f32_16x16x32_bf16(
                    afr[h][mt], bf.v, acc[mt], 0, 0, 0);
        }
        // 5) rotate ping-pong (register renames after unroll)
#pragma unroll
        for (int c = 0; c < 8; ++c) gcur[c] = gnxt[c];
#pragma unroll
        for (int c = 0; c < 4; ++c) wcur[c] = wnxt[c];
    }

#pragma unroll
    for (int mt = 0; mt < 4; ++mt)
#pragma unroll
        for (int j = 0; j < 4; ++j) {
            const int co = mt * 16 + lg * 4 + j;
            out[(((size_t)(b * CC + co)) * HH + y) * WW + x] = acc[mt][j];
        }
}

// ---------------------------------------------------------------------------
// Workspace:
//   in_nhwc  bf16  33,554,432
//   est_nhwc bf16  33,554,432
//   offs     f32    9,437,184
//   wEb      bf16     294,912
//   wOb      bf16      73,728
//   wDb      bf16      73,728
// total ~77 MB
// ---------------------------------------------------------------------------
extern "C" void kernel_launch(void* const* d_in, const int* in_sizes, int n_in,
                              void* d_out, int out_size, void* d_ws, size_t ws_size,
                              hipStream_t stream) {
    const float* lr    = (const float*)d_in[0];
    const float* hr    = (const float*)d_in[1];
    const float* w_est = (const float*)d_in[2];
    const float* w_off = (const float*)d_in[3];
    const float* w_def = (const float*)d_in[4];
    float* out = (float*)d_out;

    char* ws = (char*)d_ws;
    ushort* in_nhwc  = (ushort*)ws;   ws += (size_t)BB * HH * WW * 128 * 2;
    ushort* est_nhwc = (ushort*)ws;   ws += (size_t)BB * HH * WW * 128 * 2;
    float*  offs     = (float*)ws;    ws += (size_t)BB * 18 * HW * 4;
    ushort* wEb      = (ushort*)ws;   ws += (size_t)128 * 1152 * 2;
    ushort* wOb      = (ushort*)ws;   ws += (size_t)32 * 1152 * 2;
    ushort* wDb      = (ushort*)ws;

    pack_wE<<<(128 * 1152 + 255) / 256, 256, 0, stream>>>(w_est, wEb);
    pack_wO<<<(32 * 1152 + 255) / 256, 256, 0, stream>>>(w_off, wOb);
    pack_wD<<<(64 * 576 + 255) / 256, 256, 0, stream>>>(w_def, wDb);

    to_nhwc_bf16<<<BB * HH, 256, 0, stream>>>(lr, hr, in_nhwc);

    conv1_mfma<<<BB * HH, 256, 0, stream>>>(in_nhwc, wEb, est_nhwc);
    conv2_mfma<<<BB * HH, 256, 0, stream>>>(est_nhwc, wOb, offs);

    deform_mfma<<<BB * HH * 2, 256, 0, stream>>>(in_nhwc, offs, wDb, out);
}

// Round 5
// 254.256 us; speedup vs baseline: 4.1932x; 1.2196x over previous
//
#include <hip/hip_runtime.h>
#include <hip/hip_bf16.h>

// DeformableConvBlock: B=8, C=64, H=W=128
#define BB 8
#define CC 64
#define C2 128
#define HH 128
#define WW 128
#define HW (HH * WW)

typedef __attribute__((ext_vector_type(8))) short bf16x8;
typedef __attribute__((ext_vector_type(4))) float f32x4;

__device__ inline ushort f2bf(float f) {
    union { float f; unsigned u; } v; v.f = f;
    unsigned r = v.u + 0x7fff + ((v.u >> 16) & 1);   // RNE
    return (ushort)(r >> 16);
}
__device__ inline float bf2f(ushort u) {
    union { unsigned u; float f; } v; v.u = (unsigned)u << 16; return v.f;
}

// ---------------------------------------------------------------------------
// Pre-pass: concat(lr,hr) fp32 NCHW -> bf16 NHWC [b][y][x][128ci]
// ---------------------------------------------------------------------------
__global__ __launch_bounds__(256) void to_nhwc_bf16(
    const float* __restrict__ lr, const float* __restrict__ hr,
    ushort* __restrict__ dst) {
    __shared__ ushort lt[HH][136];
    const int t = threadIdx.x;
    const int b = blockIdx.x >> 7, y = blockIdx.x & 127;
    for (int ci0 = 0; ci0 < 128; ci0 += 2) {
        const int ci = ci0 + (t >> 7);
        const int x = t & 127;
        const float* s = (ci < 64) ? lr + ((size_t)(b * 64 + ci)) * HW
                                   : hr + ((size_t)(b * 64 + ci - 64)) * HW;
        lt[x][ci] = f2bf(s[y * WW + x]);
    }
    __syncthreads();
    ushort* db = dst + ((size_t)blockIdx.x) * WW * 128;
    for (int i = t; i < 128 * 16; i += 256) {
        const int px = i >> 4, q = i & 15;
        uint4 v = *(const uint4*)&lt[px][q * 8];
        *(uint4*)&db[(size_t)px * 128 + q * 8] = v;
    }
}

// ---------------------------------------------------------------------------
// Weight packs.
// conv weights: k = (cc*9 + tap)*32 + ci_sub   (cc = ci>>5)
// deform weights: [tap][co][c] with XOR swizzle baked in (16B-granule):
//   pos = tap*4096 + co*64 + (((c>>3) ^ (co&7))<<3) + (c&7)
// ---------------------------------------------------------------------------
__global__ void pack_wE(const float* __restrict__ w, ushort* __restrict__ o_) {
    int i = blockIdx.x * 256 + threadIdx.x;
    if (i >= 128 * 1152) return;
    int o = i / 1152, k = i % 1152;
    int cc = k / 288, rem = k % 288, tap = rem / 32, cs = rem % 32;
    int ci = cc * 32 + cs;
    o_[i] = f2bf(w[((size_t)o * 128 + ci) * 9 + tap]);
}
__global__ void pack_wO(const float* __restrict__ w, ushort* __restrict__ o_) {
    int i = blockIdx.x * 256 + threadIdx.x;
    if (i >= 32 * 1152) return;
    int o = i / 1152, k = i % 1152;
    int cc = k / 288, rem = k % 288, tap = rem / 32, cs = rem % 32;
    int ci = cc * 32 + cs;
    o_[i] = (o < 18) ? f2bf(w[((size_t)o * 128 + ci) * 9 + tap]) : (ushort)0;
}
__global__ void pack_wDk(const float* __restrict__ w, ushort* __restrict__ o_) {
    int i = blockIdx.x * 256 + threadIdx.x;
    if (i >= 9 * 4096) return;
    int tap = i / 4096, r = i % 4096, co = r / 64, c = r % 64;
    int pos = tap * 4096 + co * 64 + ((((c >> 3) ^ (co & 7))) << 3) + (c & 7);
    o_[pos] = f2bf(w[((size_t)co * 64 + c) * 9 + tap]);
}

// ---------------------------------------------------------------------------
// Stage one ci-chunk (32 ci) of a 3-row input window into LDS [3][130][40]
// ---------------------------------------------------------------------------
__device__ inline void stage_chunk(const ushort* __restrict__ nhwc_b, int y, int cc,
                                   ushort* __restrict__ lds) {
    for (int idx = threadIdx.x; idx < 3 * 130 * 4; idx += 256) {
        const int q  = idx & 3;
        const int px = (idx >> 2) % 130;
        const int r  = idx / 520;
        const int yy = y + r - 1;
        const int xx = px - 1;
        uint4 v = {0u, 0u, 0u, 0u};
        if ((unsigned)yy < (unsigned)HH && (unsigned)xx < (unsigned)WW)
            v = *(const uint4*)(nhwc_b + ((size_t)yy * WW + xx) * 128 + cc * 32 + q * 8);
        *(uint4*)(lds + (r * 130 + px) * 40 + q * 8) = v;
    }
}

// ---------------------------------------------------------------------------
// conv1: implicit-GEMM MFMA. est = leaky(conv(concat)) -> bf16 NHWC
// ---------------------------------------------------------------------------
__global__ __launch_bounds__(256) void conv1_mfma(
    const ushort* __restrict__ nhwc, const ushort* __restrict__ wEb,
    ushort* __restrict__ est) {
    __shared__ ushort lds[3 * 130 * 40];
    const int t = threadIdx.x, lane = t & 63, wid = t >> 6;
    const int wm = wid >> 1, wn = wid & 1;
    const int b = blockIdx.x >> 7, y = blockIdx.x & 127;
    const int l15 = lane & 15, lg = lane >> 4;
    const ushort* nb = nhwc + (size_t)(b * HH) * WW * 128;

    f32x4 acc[4][4] = {};
    for (int cc = 0; cc < 4; ++cc) {
        __syncthreads();
        stage_chunk(nb, y, cc, lds);
        __syncthreads();
#pragma unroll
        for (int tap = 0; tap < 9; ++tap) {
            const int ky = tap / 3, kx = tap % 3;
            bf16x8 a[4], w[4];
#pragma unroll
            for (int mt = 0; mt < 4; ++mt) {
                const int pxi = wm * 64 + mt * 16 + l15 + kx;
                a[mt] = *(const bf16x8*)&lds[(ky * 130 + pxi) * 40 + lg * 8];
            }
            const int kb = (cc * 9 + tap) * 32 + lg * 8;
#pragma unroll
            for (int nt = 0; nt < 4; ++nt) {
                const int co = wn * 64 + nt * 16 + l15;
                w[nt] = *(const bf16x8*)&wEb[(size_t)co * 1152 + kb];
            }
#pragma unroll
            for (int mt = 0; mt < 4; ++mt)
#pragma unroll
                for (int nt = 0; nt < 4; ++nt)
                    acc[mt][nt] = __builtin_amdgcn_mfma_f32_16x16x32_bf16(
                        a[mt], w[nt], acc[mt][nt], 0, 0, 0);
        }
    }
    ushort* eb = est + ((size_t)blockIdx.x) * WW * 128;
#pragma unroll
    for (int mt = 0; mt < 4; ++mt)
#pragma unroll
        for (int nt = 0; nt < 4; ++nt)
#pragma unroll
            for (int j = 0; j < 4; ++j) {
                float r = acc[mt][nt][j];
                r = (r >= 0.f) ? r : 0.1f * r;
                const int px = wm * 64 + mt * 16 + lg * 4 + j;
                const int co = wn * 64 + nt * 16 + l15;
                eb[(size_t)px * 128 + co] = f2bf(r);
            }
}

// ---------------------------------------------------------------------------
// conv2: offsets = conv(est).  A = wOb (32 rows, 18 valid), B = est pixels.
// ---------------------------------------------------------------------------
__global__ __launch_bounds__(256) void conv2_mfma(
    const ushort* __restrict__ est, const ushort* __restrict__ wOb,
    float* __restrict__ offs) {
    __shared__ ushort lds[3 * 130 * 40];
    const int t = threadIdx.x, lane = t & 63, wid = t >> 6;
    const int b = blockIdx.x >> 7, y = blockIdx.x & 127;
    const int l15 = lane & 15, lg = lane >> 4;
    const ushort* ebase = est + (size_t)(b * HH) * WW * 128;

    f32x4 acc[2][2] = {};
    for (int cc = 0; cc < 4; ++cc) {
        __syncthreads();
        stage_chunk(ebase, y, cc, lds);
        __syncthreads();
#pragma unroll
        for (int tap = 0; tap < 9; ++tap) {
            const int ky = tap / 3, kx = tap % 3;
            const int kb = (cc * 9 + tap) * 32 + lg * 8;
            bf16x8 a[2], bb[2];
#pragma unroll
            for (int mt = 0; mt < 2; ++mt)
                a[mt] = *(const bf16x8*)&wOb[(size_t)(mt * 16 + l15) * 1152 + kb];
#pragma unroll
            for (int nt = 0; nt < 2; ++nt) {
                const int pxi = wid * 32 + nt * 16 + l15 + kx;
                bb[nt] = *(const bf16x8*)&lds[(ky * 130 + pxi) * 40 + lg * 8];
            }
#pragma unroll
            for (int mt = 0; mt < 2; ++mt)
#pragma unroll
                for (int nt = 0; nt < 2; ++nt)
                    acc[mt][nt] = __builtin_amdgcn_mfma_f32_16x16x32_bf16(
                        a[mt], bb[nt], acc[mt][nt], 0, 0, 0);
        }
    }
    float* ob = offs + (size_t)b * 18 * HW + (size_t)y * WW;
#pragma unroll
    for (int mt = 0; mt < 2; ++mt)
#pragma unroll
        for (int nt = 0; nt < 2; ++nt)
#pragma unroll
            for (int j = 0; j < 4; ++j) {
                const int co = mt * 16 + lg * 4 + j;
                if (co < 18) {
                    const int px = wid * 32 + nt * 16 + l15;
                    ob[(size_t)co * HW + px] = acc[mt][nt][j];
                }
            }
}

// ---------------------------------------------------------------------------
// Deformable conv v3: MFMA + per-tap weight slice staged in LDS.
// Block = 4 waves covering 2 rows x 32 px (tap-synced); wave = 16px x 64co.
// Per tap: stage next tap's 8KB weight slice (dense, reg-staged, dbuf,
// 1 barrier); A-frags via swizzled ds_read_b128 (pre-swizzled pack, m173);
// gathers stay scattered (now sole consumers of L1).
// ---------------------------------------------------------------------------
__device__ inline void def_coords(const ushort* __restrict__ nb, int y, int x,
                                  int k, float dy, float dx, int chan_base,
                                  float* __restrict__ w,
                                  const ushort** __restrict__ p) {
    const int ky = k / 3 - 1, kx = k % 3 - 1;
    const float py  = (float)(y + ky) + dy;
    const float pxf = (float)(x + kx) + dx;
    const float y0f = floorf(py), x0f = floorf(pxf);
    const float wy1 = py - y0f, wx1 = pxf - x0f;
    const float wy0 = 1.f - wy1, wx0 = 1.f - wx1;
    const int y0 = (int)y0f, x0 = (int)x0f;
    const int y1 = y0 + 1, x1 = x0 + 1;
    const bool vy0 = (unsigned)y0 < (unsigned)HH;
    const bool vy1 = (unsigned)y1 < (unsigned)HH;
    const bool vx0 = (unsigned)x0 < (unsigned)WW;
    const bool vx1 = (unsigned)x1 < (unsigned)WW;
    w[0] = wy0 * wx0 * ((vy0 && vx0) ? 1.f : 0.f);
    w[1] = wy0 * wx1 * ((vy0 && vx1) ? 1.f : 0.f);
    w[2] = wy1 * wx0 * ((vy1 && vx0) ? 1.f : 0.f);
    w[3] = wy1 * wx1 * ((vy1 && vx1) ? 1.f : 0.f);
    const int y0c = min(max(y0, 0), HH - 1), y1c = min(max(y1, 0), HH - 1);
    const int x0c = min(max(x0, 0), WW - 1), x1c = min(max(x1, 0), WW - 1);
    p[0] = nb + ((size_t)y0c * WW + x0c) * 128 + chan_base;
    p[1] = nb + ((size_t)y0c * WW + x1c) * 128 + chan_base;
    p[2] = nb + ((size_t)y1c * WW + x0c) * 128 + chan_base;
    p[3] = nb + ((size_t)y1c * WW + x1c) * 128 + chan_base;
}

__global__ __launch_bounds__(256) void deform_mfma(
    const ushort* __restrict__ nhwc,   // [b][y][x][128]
    const float* __restrict__ offs,    // [b][18][H][W]
    const ushort* __restrict__ wDk,    // [9][64][64] pre-swizzled
    float* __restrict__ out) {         // [b][64][H][W]
    __shared__ ushort wlds[2][4096];   // 16 KB, per-tap weight slice (dbuf)
    const int t = threadIdx.x, lane = t & 63, wid = t >> 6;
    const int l15 = lane & 15, lg = lane >> 4;
    const int bi = blockIdx.x;
    const int xq = bi & 3;             // 4 x-quads of 32 px
    const int yp = (bi >> 2) & 63;     // row pair
    const int b  = bi >> 8;
    const int y = yp * 2 + (wid >> 1);
    const int x = xq * 32 + (wid & 1) * 16 + l15;

    const ushort* nb = nhwc + (size_t)(b * HH) * WW * 128;
    const float* ob = offs + (size_t)b * 18 * HW + (size_t)y * WW + x;
    const int cb = 64 + lg * 8;        // hr channels live at +64 in concat buf

    // preload all 18 offset scalars (coalesced, one drain)
    float dyv[9], dxv[9];
#pragma unroll
    for (int k = 0; k < 9; ++k) {
        dyv[k] = ob[(size_t)(2 * k) * HW];
        dxv[k] = ob[(size_t)(2 * k + 1) * HW];
    }

    // prologue: stage tap-0 weight slice
    {
        uint4 a0 = *(const uint4*)(wDk + t * 16);
        uint4 a1 = *(const uint4*)(wDk + t * 16 + 8);
        *(uint4*)&wlds[0][t * 16]     = a0;
        *(uint4*)&wlds[0][t * 16 + 8] = a1;
    }
    __syncthreads();

    f32x4 acc[4] = {};
#pragma unroll
    for (int k = 0; k < 9; ++k) {
        const int cur = k & 1, nxt = cur ^ 1;
        // 1) issue next tap's weight-slice loads (dense; land during compute)
        uint4 n0, n1;
        if (k < 8) {
            n0 = *(const uint4*)(wDk + (k + 1) * 4096 + t * 16);
            n1 = *(const uint4*)(wDk + (k + 1) * 4096 + t * 16 + 8);
        }
        // 2) issue this tap's gathers (scattered; sole L1 consumers now)
        float wz[4]; const ushort* p[4];
        def_coords(nb, y, x, k, dyv[k], dxv[k], cb, wz, p);
        bf16x8 g[8];
#pragma unroll
        for (int c = 0; c < 4; ++c) {
            g[c]     = *(const bf16x8*)(p[c]);         // channels [lg*8, lg*8+8)
            g[4 + c] = *(const bf16x8*)(p[c] + 32);    // +32 channels
        }
        // 3) per-half: swizzled ds_read A-frags, blend, MFMA
#pragma unroll
        for (int h = 0; h < 2; ++h) {
            const int sw = (h * 4 + lg) ^ (l15 & 7);
            bf16x8 afr[4];
#pragma unroll
            for (int mt = 0; mt < 4; ++mt)
                afr[mt] = *(const bf16x8*)&wlds[cur][(mt * 16 + l15) * 64 + sw * 8];
            float s[8];
#pragma unroll
            for (int j = 0; j < 8; ++j)
                s[j] = wz[0] * bf2f((ushort)g[h * 4 + 0][j])
                     + wz[1] * bf2f((ushort)g[h * 4 + 1][j])
                     + wz[2] * bf2f((ushort)g[h * 4 + 2][j])
                     + wz[3] * bf2f((ushort)g[h * 4 + 3][j]);
            union { unsigned u[4]; bf16x8 v; } bf;
#pragma unroll
            for (int j2 = 0; j2 < 4; ++j2) {
                __hip_bfloat162 hh =
                    __float22bfloat162_rn(make_float2(s[2 * j2], s[2 * j2 + 1]));
                __builtin_memcpy(&bf.u[j2], &hh, 4);
            }
#pragma unroll
            for (int mt = 0; mt < 4; ++mt)
                acc[mt] = __builtin_amdgcn_mfma_f32_16x16x32_bf16(
                    afr[mt], bf.v, acc[mt], 0, 0, 0);
        }
        // 4) write next tap's slice, barrier (protects both buffers)
        if (k < 8) {
            *(uint4*)&wlds[nxt][t * 16]     = n0;
            *(uint4*)&wlds[nxt][t * 16 + 8] = n1;
        }
        __syncthreads();
    }

#pragma unroll
    for (int mt = 0; mt < 4; ++mt)
#pragma unroll
        for (int j = 0; j < 4; ++j) {
            const int co = mt * 16 + lg * 4 + j;
            out[(((size_t)(b * CC + co)) * HH + y) * WW + x] = acc[mt][j];
        }
}

// ---------------------------------------------------------------------------
// Workspace:
//   in_nhwc  bf16  33,554,432
//   est_nhwc bf16  33,554,432
//   offs     f32    9,437,184
//   wEb      bf16     294,912
//   wOb      bf16      73,728
//   wDk      bf16      73,728
// total ~77 MB
// ---------------------------------------------------------------------------
extern "C" void kernel_launch(void* const* d_in, const int* in_sizes, int n_in,
                              void* d_out, int out_size, void* d_ws, size_t ws_size,
                              hipStream_t stream) {
    const float* lr    = (const float*)d_in[0];
    const float* hr    = (const float*)d_in[1];
    const float* w_est = (const float*)d_in[2];
    const float* w_off = (const float*)d_in[3];
    const float* w_def = (const float*)d_in[4];
    float* out = (float*)d_out;

    char* ws = (char*)d_ws;
    ushort* in_nhwc  = (ushort*)ws;   ws += (size_t)BB * HH * WW * 128 * 2;
    ushort* est_nhwc = (ushort*)ws;   ws += (size_t)BB * HH * WW * 128 * 2;
    float*  offs     = (float*)ws;    ws += (size_t)BB * 18 * HW * 4;
    ushort* wEb      = (ushort*)ws;   ws += (size_t)128 * 1152 * 2;
    ushort* wOb      = (ushort*)ws;   ws += (size_t)32 * 1152 * 2;
    ushort* wDk      = (ushort*)ws;

    pack_wE<<<(128 * 1152 + 255) / 256, 256, 0, stream>>>(w_est, wEb);
    pack_wO<<<(32 * 1152 + 255) / 256, 256, 0, stream>>>(w_off, wOb);
    pack_wDk<<<(9 * 4096 + 255) / 256, 256, 0, stream>>>(w_def, wDk);

    to_nhwc_bf16<<<BB * HH, 256, 0, stream>>>(lr, hr, in_nhwc);

    conv1_mfma<<<BB * HH, 256, 0, stream>>>(in_nhwc, wEb, est_nhwc);
    conv2_mfma<<<BB * HH, 256, 0, stream>>>(est_nhwc, wOb, offs);

    deform_mfma<<<BB * HH * 2, 256, 0, stream>>>(in_nhwc, offs, wDk, out);
}

// Round 6
// 198.975 us; speedup vs baseline: 5.3582x; 1.2778x over previous
//
#include <hip/hip_runtime.h>
#include <hip/hip_bf16.h>

// DeformableConvBlock: B=8, C=64, H=W=128
#define BB 8
#define CC 64
#define C2 128
#define HH 128
#define WW 128
#define HW (HH * WW)

typedef __attribute__((ext_vector_type(8))) short bf16x8;
typedef __attribute__((ext_vector_type(4))) float f32x4;

__device__ inline ushort f2bf(float f) {
    union { float f; unsigned u; } v; v.f = f;
    unsigned r = v.u + 0x7fff + ((v.u >> 16) & 1);   // RNE
    return (ushort)(r >> 16);
}
__device__ inline float bf2f(ushort u) {
    union { unsigned u; float f; } v; v.u = (unsigned)u << 16; return v.f;
}

// ---------------------------------------------------------------------------
// Pre-pass: concat(lr,hr) fp32 NCHW -> bf16 NHWC [b][y][x][128ci]
// ---------------------------------------------------------------------------
__global__ __launch_bounds__(256) void to_nhwc_bf16(
    const float* __restrict__ lr, const float* __restrict__ hr,
    ushort* __restrict__ dst) {
    __shared__ ushort lt[HH][136];
    const int t = threadIdx.x;
    const int b = blockIdx.x >> 7, y = blockIdx.x & 127;
    for (int ci0 = 0; ci0 < 128; ci0 += 2) {
        const int ci = ci0 + (t >> 7);
        const int x = t & 127;
        const float* s = (ci < 64) ? lr + ((size_t)(b * 64 + ci)) * HW
                                   : hr + ((size_t)(b * 64 + ci - 64)) * HW;
        lt[x][ci] = f2bf(s[y * WW + x]);
    }
    __syncthreads();
    ushort* db = dst + ((size_t)blockIdx.x) * WW * 128;
    for (int i = t; i < 128 * 16; i += 256) {
        const int px = i >> 4, q = i & 15;
        uint4 v = *(const uint4*)&lt[px][q * 8];
        *(uint4*)&db[(size_t)px * 128 + q * 8] = v;
    }
}

// ---------------------------------------------------------------------------
// Weight packs.
// conv1 weights wE2: [kb][co][8] where kb = (cc*9+tap)*4+lg, ci = cc*32+lg*8+c7
// conv2 weights wOb: k = (cc*9 + tap)*32 + ci_sub (old layout, unchanged)
// deform weights wDk: [tap][co][c] with XOR swizzle baked in
// ---------------------------------------------------------------------------
__global__ void pack_wE2(const float* __restrict__ w, ushort* __restrict__ o_) {
    int i = blockIdx.x * 256 + threadIdx.x;
    if (i >= 128 * 1152) return;
    int c7 = i & 7, co = (i >> 3) & 127, kb = i >> 10;
    int lg = kb & 3, ct = kb >> 2, tap = ct % 9, cc = ct / 9;
    int ci = cc * 32 + lg * 8 + c7;
    o_[i] = f2bf(w[((size_t)co * 128 + ci) * 9 + tap]);
}
__global__ void pack_wO(const float* __restrict__ w, ushort* __restrict__ o_) {
    int i = blockIdx.x * 256 + threadIdx.x;
    if (i >= 32 * 1152) return;
    int o = i / 1152, k = i % 1152;
    int cc = k / 288, rem = k % 288, tap = rem / 32, cs = rem % 32;
    int ci = cc * 32 + cs;
    o_[i] = (o < 18) ? f2bf(w[((size_t)o * 128 + ci) * 9 + tap]) : (ushort)0;
}
__global__ void pack_wDk(const float* __restrict__ w, ushort* __restrict__ o_) {
    int i = blockIdx.x * 256 + threadIdx.x;
    if (i >= 9 * 4096) return;
    int tap = i / 4096, r = i % 4096, co = r / 64, c = r % 64;
    int pos = tap * 4096 + co * 64 + ((((c >> 3) ^ (co & 7))) << 3) + (c & 7);
    o_[pos] = f2bf(w[((size_t)co * 64 + c) * 9 + tap]);
}

// ---------------------------------------------------------------------------
// Old stage (conv2 only): one ci-chunk of a 3-row window -> LDS [3][130][40]
// ---------------------------------------------------------------------------
__device__ inline void stage_chunk(const ushort* __restrict__ nhwc_b, int y, int cc,
                                   ushort* __restrict__ lds) {
    for (int idx = threadIdx.x; idx < 3 * 130 * 4; idx += 256) {
        const int q  = idx & 3;
        const int px = (idx >> 2) % 130;
        const int r  = idx / 520;
        const int yy = y + r - 1;
        const int xx = px - 1;
        uint4 v = {0u, 0u, 0u, 0u};
        if ((unsigned)yy < (unsigned)HH && (unsigned)xx < (unsigned)WW)
            v = *(const uint4*)(nhwc_b + ((size_t)yy * WW + xx) * 128 + cc * 32 + q * 8);
        *(uint4*)(lds + (r * 130 + px) * 40 + q * 8) = v;
    }
}

// ---------------------------------------------------------------------------
// conv1 v2: 4-row tile, 512 thr (8 waves = 4 rows x 2 co-halves), dbuf LDS
// staged via global_load_lds (zero-page for OOB), conflict-free layout
// [6r][4q][130px][8ci].  Weights [kb][co][8] -> contiguous 256B frag loads.
// ---------------------------------------------------------------------------
#define SLOTS 3120         // 6*4*130
#define SLOTS_PAD 3136

__global__ __launch_bounds__(512) void conv1_mfma(
    const ushort* __restrict__ nhwc, const ushort* __restrict__ wE2,
    const ushort* __restrict__ zp, ushort* __restrict__ est) {
    __shared__ ushort lws[2][SLOTS_PAD * 8];   // 2 x 50,176 B
    const int t = threadIdx.x, lane = t & 63, wid = t >> 6;
    const int l15 = lane & 15, lg = lane >> 4;
    const int wm = wid >> 1, wn = wid & 1;     // row-in-tile, co-half
    const int b = blockIdx.x >> 5, yt = blockIdx.x & 31;
    const int y0 = yt * 4;
    const ushort* nb = nhwc + (size_t)(b * HH) * WW * 128;

    auto stage = [&](int cc, int bf) {
        for (int s0 = wid * 64; s0 < SLOTS; s0 += 512) {
            const int s = s0 + lane;
            const int sc = (s < SLOTS) ? s : (SLOTS - 1);
            const int plane = sc / 130, px = sc % 130;
            const int r = plane >> 2, q = plane & 3;
            const int yy = y0 + r - 1, xx = px - 1;
            const ushort* g =
                ((unsigned)yy < (unsigned)HH && (unsigned)xx < (unsigned)WW)
                    ? nb + ((size_t)yy * WW + xx) * 128 + cc * 32 + q * 8
                    : zp;
            __builtin_amdgcn_global_load_lds(
                (const __attribute__((address_space(1))) void*)g,
                (__attribute__((address_space(3))) void*)(&lws[bf][s0 * 8]),
                16, 0, 0);
        }
    };

    f32x4 acc[8][4] = {};
    stage(0, 0);
    __syncthreads();
#pragma unroll
    for (int cc = 0; cc < 4; ++cc) {
        if (cc < 3) stage(cc + 1, (cc + 1) & 1);   // in flight during compute
        const ushort* buf = lws[cc & 1];
#pragma unroll
        for (int tap = 0; tap < 9; ++tap) {
            const int ky = tap / 3, kx = tap % 3;
            bf16x8 a[8], w[4];
#pragma unroll
            for (int mt = 0; mt < 8; ++mt)
                a[mt] = *(const bf16x8*)
                    &buf[(((wm + ky) * 4 + lg) * 130 + mt * 16 + l15 + kx) * 8];
#pragma unroll
            for (int nt = 0; nt < 4; ++nt)
                w[nt] = *(const bf16x8*)&wE2[(size_t)(((cc * 9 + tap) * 4 + lg) * 128
                                                     + wn * 64 + nt * 16 + l15) * 8];
#pragma unroll
            for (int mt = 0; mt < 8; ++mt)
#pragma unroll
                for (int nt = 0; nt < 4; ++nt)
                    acc[mt][nt] = __builtin_amdgcn_mfma_f32_16x16x32_bf16(
                        a[mt], w[nt], acc[mt][nt], 0, 0, 0);
        }
        __syncthreads();   // drains stage(cc+1) (vmcnt0) + protects buffers
    }

    const int y = y0 + wm;
    ushort* eb = est + ((size_t)(b * HH + y)) * WW * 128;
#pragma unroll
    for (int mt = 0; mt < 8; ++mt)
#pragma unroll
        for (int nt = 0; nt < 4; ++nt)
#pragma unroll
            for (int j = 0; j < 4; ++j) {
                float r = acc[mt][nt][j];
                r = (r >= 0.f) ? r : 0.1f * r;
                eb[(size_t)(mt * 16 + lg * 4 + j) * 128
                   + wn * 64 + nt * 16 + l15] = f2bf(r);
            }
}

// ---------------------------------------------------------------------------
// conv2: offsets = conv(est).  Unchanged from round 5.
// ---------------------------------------------------------------------------
__global__ __launch_bounds__(256) void conv2_mfma(
    const ushort* __restrict__ est, const ushort* __restrict__ wOb,
    float* __restrict__ offs) {
    __shared__ ushort lds[3 * 130 * 40];
    const int t = threadIdx.x, lane = t & 63, wid = t >> 6;
    const int b = blockIdx.x >> 7, y = blockIdx.x & 127;
    const int l15 = lane & 15, lg = lane >> 4;
    const ushort* ebase = est + (size_t)(b * HH) * WW * 128;

    f32x4 acc[2][2] = {};
    for (int cc = 0; cc < 4; ++cc) {
        __syncthreads();
        stage_chunk(ebase, y, cc, lds);
        __syncthreads();
#pragma unroll
        for (int tap = 0; tap < 9; ++tap) {
            const int ky = tap / 3, kx = tap % 3;
            const int kb = (cc * 9 + tap) * 32 + lg * 8;
            bf16x8 a[2], bb[2];
#pragma unroll
            for (int mt = 0; mt < 2; ++mt)
                a[mt] = *(const bf16x8*)&wOb[(size_t)(mt * 16 + l15) * 1152 + kb];
#pragma unroll
            for (int nt = 0; nt < 2; ++nt) {
                const int pxi = wid * 32 + nt * 16 + l15 + kx;
                bb[nt] = *(const bf16x8*)&lds[(ky * 130 + pxi) * 40 + lg * 8];
            }
#pragma unroll
            for (int mt = 0; mt < 2; ++mt)
#pragma unroll
                for (int nt = 0; nt < 2; ++nt)
                    acc[mt][nt] = __builtin_amdgcn_mfma_f32_16x16x32_bf16(
                        a[mt], bb[nt], acc[mt][nt], 0, 0, 0);
        }
    }
    float* ob = offs + (size_t)b * 18 * HW + (size_t)y * WW;
#pragma unroll
    for (int mt = 0; mt < 2; ++mt)
#pragma unroll
        for (int nt = 0; nt < 2; ++nt)
#pragma unroll
            for (int j = 0; j < 4; ++j) {
                const int co = mt * 16 + lg * 4 + j;
                if (co < 18) {
                    const int px = wid * 32 + nt * 16 + l15;
                    ob[(size_t)co * HW + px] = acc[mt][nt][j];
                }
            }
}

// ---------------------------------------------------------------------------
// Deformable conv v3 (unchanged from round 5): per-tap weight slice in LDS.
// ---------------------------------------------------------------------------
__device__ inline void def_coords(const ushort* __restrict__ nb, int y, int x,
                                  int k, float dy, float dx, int chan_base,
                                  float* __restrict__ w,
                                  const ushort** __restrict__ p) {
    const int ky = k / 3 - 1, kx = k % 3 - 1;
    const float py  = (float)(y + ky) + dy;
    const float pxf = (float)(x + kx) + dx;
    const float y0f = floorf(py), x0f = floorf(pxf);
    const float wy1 = py - y0f, wx1 = pxf - x0f;
    const float wy0 = 1.f - wy1, wx0 = 1.f - wx1;
    const int y0 = (int)y0f, x0 = (int)x0f;
    const int y1 = y0 + 1, x1 = x0 + 1;
    const bool vy0 = (unsigned)y0 < (unsigned)HH;
    const bool vy1 = (unsigned)y1 < (unsigned)HH;
    const bool vx0 = (unsigned)x0 < (unsigned)WW;
    const bool vx1 = (unsigned)x1 < (unsigned)WW;
    w[0] = wy0 * wx0 * ((vy0 && vx0) ? 1.f : 0.f);
    w[1] = wy0 * wx1 * ((vy0 && vx1) ? 1.f : 0.f);
    w[2] = wy1 * wx0 * ((vy1 && vx0) ? 1.f : 0.f);
    w[3] = wy1 * wx1 * ((vy1 && vx1) ? 1.f : 0.f);
    const int y0c = min(max(y0, 0), HH - 1), y1c = min(max(y1, 0), HH - 1);
    const int x0c = min(max(x0, 0), WW - 1), x1c = min(max(x1, 0), WW - 1);
    p[0] = nb + ((size_t)y0c * WW + x0c) * 128 + chan_base;
    p[1] = nb + ((size_t)y0c * WW + x1c) * 128 + chan_base;
    p[2] = nb + ((size_t)y1c * WW + x0c) * 128 + chan_base;
    p[3] = nb + ((size_t)y1c * WW + x1c) * 128 + chan_base;
}

__global__ __launch_bounds__(256) void deform_mfma(
    const ushort* __restrict__ nhwc,   // [b][y][x][128]
    const float* __restrict__ offs,    // [b][18][H][W]
    const ushort* __restrict__ wDk,    // [9][64][64] pre-swizzled
    float* __restrict__ out) {         // [b][64][H][W]
    __shared__ ushort wlds[2][4096];
    const int t = threadIdx.x, lane = t & 63, wid = t >> 6;
    const int l15 = lane & 15, lg = lane >> 4;
    const int bi = blockIdx.x;
    const int xq = bi & 3;
    const int yp = (bi >> 2) & 63;
    const int b  = bi >> 8;
    const int y = yp * 2 + (wid >> 1);
    const int x = xq * 32 + (wid & 1) * 16 + l15;

    const ushort* nb = nhwc + (size_t)(b * HH) * WW * 128;
    const float* ob = offs + (size_t)b * 18 * HW + (size_t)y * WW + x;
    const int cb = 64 + lg * 8;

    float dyv[9], dxv[9];
#pragma unroll
    for (int k = 0; k < 9; ++k) {
        dyv[k] = ob[(size_t)(2 * k) * HW];
        dxv[k] = ob[(size_t)(2 * k + 1) * HW];
    }

    {
        uint4 a0 = *(const uint4*)(wDk + t * 16);
        uint4 a1 = *(const uint4*)(wDk + t * 16 + 8);
        *(uint4*)&wlds[0][t * 16]     = a0;
        *(uint4*)&wlds[0][t * 16 + 8] = a1;
    }
    __syncthreads();

    f32x4 acc[4] = {};
#pragma unroll
    for (int k = 0; k < 9; ++k) {
        const int cur = k & 1, nxt = cur ^ 1;
        uint4 n0, n1;
        if (k < 8) {
            n0 = *(const uint4*)(wDk + (k + 1) * 4096 + t * 16);
            n1 = *(const uint4*)(wDk + (k + 1) * 4096 + t * 16 + 8);
        }
        float wz[4]; const ushort* p[4];
        def_coords(nb, y, x, k, dyv[k], dxv[k], cb, wz, p);
        bf16x8 g[8];
#pragma unroll
        for (int c = 0; c < 4; ++c) {
            g[c]     = *(const bf16x8*)(p[c]);
            g[4 + c] = *(const bf16x8*)(p[c] + 32);
        }
#pragma unroll
        for (int h = 0; h < 2; ++h) {
            const int sw = (h * 4 + lg) ^ (l15 & 7);
            bf16x8 afr[4];
#pragma unroll
            for (int mt = 0; mt < 4; ++mt)
                afr[mt] = *(const bf16x8*)&wlds[cur][(mt * 16 + l15) * 64 + sw * 8];
            float s[8];
#pragma unroll
            for (int j = 0; j < 8; ++j)
                s[j] = wz[0] * bf2f((ushort)g[h * 4 + 0][j])
                     + wz[1] * bf2f((ushort)g[h * 4 + 1][j])
                     + wz[2] * bf2f((ushort)g[h * 4 + 2][j])
                     + wz[3] * bf2f((ushort)g[h * 4 + 3][j]);
            union { unsigned u[4]; bf16x8 v; } bf;
#pragma unroll
            for (int j2 = 0; j2 < 4; ++j2) {
                __hip_bfloat162 hh =
                    __float22bfloat162_rn(make_float2(s[2 * j2], s[2 * j2 + 1]));
                __builtin_memcpy(&bf.u[j2], &hh, 4);
            }
#pragma unroll
            for (int mt = 0; mt < 4; ++mt)
                acc[mt] = __builtin_amdgcn_mfma_f32_16x16x32_bf16(
                    afr[mt], bf.v, acc[mt], 0, 0, 0);
        }
        if (k < 8) {
            *(uint4*)&wlds[nxt][t * 16]     = n0;
            *(uint4*)&wlds[nxt][t * 16 + 8] = n1;
        }
        __syncthreads();
    }

#pragma unroll
    for (int mt = 0; mt < 4; ++mt)
#pragma unroll
        for (int j = 0; j < 4; ++j) {
            const int co = mt * 16 + lg * 4 + j;
            out[(((size_t)(b * CC + co)) * HH + y) * WW + x] = acc[mt][j];
        }
}

// ---------------------------------------------------------------------------
// Workspace:
//   in_nhwc  bf16  33,554,432
//   est_nhwc bf16  33,554,432
//   offs     f32    9,437,184
//   wE2      bf16     294,912
//   wOb      bf16      73,728
//   wDk      bf16      73,728
//   zpage             256 (zeroed each launch)
// total ~77 MB
// ---------------------------------------------------------------------------
extern "C" void kernel_launch(void* const* d_in, const int* in_sizes, int n_in,
                              void* d_out, int out_size, void* d_ws, size_t ws_size,
                              hipStream_t stream) {
    const float* lr    = (const float*)d_in[0];
    const float* hr    = (const float*)d_in[1];
    const float* w_est = (const float*)d_in[2];
    const float* w_off = (const float*)d_in[3];
    const float* w_def = (const float*)d_in[4];
    float* out = (float*)d_out;

    char* ws = (char*)d_ws;
    ushort* in_nhwc  = (ushort*)ws;   ws += (size_t)BB * HH * WW * 128 * 2;
    ushort* est_nhwc = (ushort*)ws;   ws += (size_t)BB * HH * WW * 128 * 2;
    float*  offs     = (float*)ws;    ws += (size_t)BB * 18 * HW * 4;
    ushort* wE2      = (ushort*)ws;   ws += (size_t)128 * 1152 * 2;
    ushort* wOb      = (ushort*)ws;   ws += (size_t)32 * 1152 * 2;
    ushort* wDk      = (ushort*)ws;   ws += (size_t)9 * 4096 * 2;
    ushort* zp       = (ushort*)ws;

    hipMemsetAsync(zp, 0, 256, stream);
    pack_wE2<<<(128 * 1152 + 255) / 256, 256, 0, stream>>>(w_est, wE2);
    pack_wO<<<(32 * 1152 + 255) / 256, 256, 0, stream>>>(w_off, wOb);
    pack_wDk<<<(9 * 4096 + 255) / 256, 256, 0, stream>>>(w_def, wDk);

    to_nhwc_bf16<<<BB * HH, 256, 0, stream>>>(lr, hr, in_nhwc);

    conv1_mfma<<<BB * (HH / 4), 512, 0, stream>>>(in_nhwc, wE2, zp, est_nhwc);
    conv2_mfma<<<BB * HH, 256, 0, stream>>>(est_nhwc, wOb, offs);

    deform_mfma<<<BB * HH * 2, 256, 0, stream>>>(in_nhwc, offs, wDk, out);
}

// Round 7
// 175.633 us; speedup vs baseline: 6.0703x; 1.1329x over previous
//
#include <hip/hip_runtime.h>
#include <hip/hip_bf16.h>

// DeformableConvBlock: B=8, C=64, H=W=128
#define BB 8
#define CC 64
#define C2 128
#define HH 128
#define WW 128
#define HW (HH * WW)

typedef __attribute__((ext_vector_type(8))) short bf16x8;
typedef __attribute__((ext_vector_type(4))) float f32x4;

__device__ inline ushort f2bf(float f) {
    union { float f; unsigned u; } v; v.f = f;
    unsigned r = v.u + 0x7fff + ((v.u >> 16) & 1);   // RNE
    return (ushort)(r >> 16);
}
__device__ inline float bf2f(ushort u) {
    union { unsigned u; float f; } v; v.u = (unsigned)u << 16; return v.f;
}

// ---------------------------------------------------------------------------
// Pre-pass: concat(lr,hr) fp32 NCHW -> bf16 NHWC [b][y][x][128ci]
// ---------------------------------------------------------------------------
__global__ __launch_bounds__(256) void to_nhwc_bf16(
    const float* __restrict__ lr, const float* __restrict__ hr,
    ushort* __restrict__ dst) {
    __shared__ ushort lt[HH][136];
    const int t = threadIdx.x;
    const int b = blockIdx.x >> 7, y = blockIdx.x & 127;
    for (int ci0 = 0; ci0 < 128; ci0 += 2) {
        const int ci = ci0 + (t >> 7);
        const int x = t & 127;
        const float* s = (ci < 64) ? lr + ((size_t)(b * 64 + ci)) * HW
                                   : hr + ((size_t)(b * 64 + ci - 64)) * HW;
        lt[x][ci] = f2bf(s[y * WW + x]);
    }
    __syncthreads();
    ushort* db = dst + ((size_t)blockIdx.x) * WW * 128;
    for (int i = t; i < 128 * 16; i += 256) {
        const int px = i >> 4, q = i & 15;
        uint4 v = *(const uint4*)&lt[px][q * 8];
        *(uint4*)&db[(size_t)px * 128 + q * 8] = v;
    }
}

// ---------------------------------------------------------------------------
// Weight packs.
// conv1 wE2: [kb][128co][8], kb=(cc*9+tap)*4+lg, ci=cc*32+lg*8+c7
// conv2 wO2: [kb][32co][8], same kb; co>=18 zero-padded
// deform wD4: [tap][h][lg][64co][8], c = h*32+lg*8+c7 (coalesced 256B frags)
// ---------------------------------------------------------------------------
__global__ void pack_wE2(const float* __restrict__ w, ushort* __restrict__ o_) {
    int i = blockIdx.x * 256 + threadIdx.x;
    if (i >= 128 * 1152) return;
    int c7 = i & 7, co = (i >> 3) & 127, kb = i >> 10;
    int lg = kb & 3, ct = kb >> 2, tap = ct % 9, cc = ct / 9;
    int ci = cc * 32 + lg * 8 + c7;
    o_[i] = f2bf(w[((size_t)co * 128 + ci) * 9 + tap]);
}
__global__ void pack_wO2(const float* __restrict__ w, ushort* __restrict__ o_) {
    int i = blockIdx.x * 256 + threadIdx.x;
    if (i >= 144 * 32 * 8) return;
    int c7 = i & 7, co = (i >> 3) & 31, kb = i >> 8;
    int lg = kb & 3, ct = kb >> 2, tap = ct % 9, cc = ct / 9;
    int ci = cc * 32 + lg * 8 + c7;
    o_[i] = (co < 18) ? f2bf(w[((size_t)co * 128 + ci) * 9 + tap]) : (ushort)0;
}
__global__ void pack_wD4(const float* __restrict__ w, ushort* __restrict__ o_) {
    int i = blockIdx.x * 256 + threadIdx.x;
    if (i >= 9 * 4096) return;
    int c7 = i & 7, co = (i >> 3) & 63, lg = (i >> 9) & 3, h = (i >> 11) & 1,
        tap = i >> 12;
    int c = h * 32 + lg * 8 + c7;
    o_[i] = f2bf(w[((size_t)co * 64 + c) * 9 + tap]);
}

// ---------------------------------------------------------------------------
// conv1 v2 (unchanged from round 6): 4-row tile, 512 thr, dbuf global_load_lds
// staging, conflict-free layout [6r][4q][130px][8ci], weights [kb][co][8].
// ---------------------------------------------------------------------------
#define SLOTS 3120         // 6*4*130
#define SLOTS_PAD 3136

__global__ __launch_bounds__(512) void conv1_mfma(
    const ushort* __restrict__ nhwc, const ushort* __restrict__ wE2,
    const ushort* __restrict__ zp, ushort* __restrict__ est) {
    __shared__ ushort lws[2][SLOTS_PAD * 8];   // 2 x 50,176 B
    const int t = threadIdx.x, lane = t & 63, wid = t >> 6;
    const int l15 = lane & 15, lg = lane >> 4;
    const int wm = wid >> 1, wn = wid & 1;     // row-in-tile, co-half
    const int b = blockIdx.x >> 5, yt = blockIdx.x & 31;
    const int y0 = yt * 4;
    const ushort* nb = nhwc + (size_t)(b * HH) * WW * 128;

    auto stage = [&](int cc, int bf) {
        for (int s0 = wid * 64; s0 < SLOTS; s0 += 512) {
            const int s = s0 + lane;
            const int sc = (s < SLOTS) ? s : (SLOTS - 1);
            const int plane = sc / 130, px = sc % 130;
            const int r = plane >> 2, q = plane & 3;
            const int yy = y0 + r - 1, xx = px - 1;
            const ushort* g =
                ((unsigned)yy < (unsigned)HH && (unsigned)xx < (unsigned)WW)
                    ? nb + ((size_t)yy * WW + xx) * 128 + cc * 32 + q * 8
                    : zp;
            __builtin_amdgcn_global_load_lds(
                (const __attribute__((address_space(1))) void*)g,
                (__attribute__((address_space(3))) void*)(&lws[bf][s0 * 8]),
                16, 0, 0);
        }
    };

    f32x4 acc[8][4] = {};
    stage(0, 0);
    __syncthreads();
#pragma unroll
    for (int cc = 0; cc < 4; ++cc) {
        if (cc < 3) stage(cc + 1, (cc + 1) & 1);
        const ushort* buf = lws[cc & 1];
#pragma unroll
        for (int tap = 0; tap < 9; ++tap) {
            const int ky = tap / 3, kx = tap % 3;
            bf16x8 a[8], w[4];
#pragma unroll
            for (int mt = 0; mt < 8; ++mt)
                a[mt] = *(const bf16x8*)
                    &buf[(((wm + ky) * 4 + lg) * 130 + mt * 16 + l15 + kx) * 8];
#pragma unroll
            for (int nt = 0; nt < 4; ++nt)
                w[nt] = *(const bf16x8*)&wE2[(size_t)(((cc * 9 + tap) * 4 + lg) * 128
                                                     + wn * 64 + nt * 16 + l15) * 8];
#pragma unroll
            for (int mt = 0; mt < 8; ++mt)
#pragma unroll
                for (int nt = 0; nt < 4; ++nt)
                    acc[mt][nt] = __builtin_amdgcn_mfma_f32_16x16x32_bf16(
                        a[mt], w[nt], acc[mt][nt], 0, 0, 0);
        }
        __syncthreads();
    }

    const int y = y0 + wm;
    ushort* eb = est + ((size_t)(b * HH + y)) * WW * 128;
#pragma unroll
    for (int mt = 0; mt < 8; ++mt)
#pragma unroll
        for (int nt = 0; nt < 4; ++nt)
#pragma unroll
            for (int j = 0; j < 4; ++j) {
                float r = acc[mt][nt][j];
                r = (r >= 0.f) ? r : 0.1f * r;
                eb[(size_t)(mt * 16 + lg * 4 + j) * 128
                   + wn * 64 + nt * 16 + l15] = f2bf(r);
            }
}

// ---------------------------------------------------------------------------
// conv2 v2: same structure as conv1 v2.  A = weights (32 co rows, 18 valid),
// B = est pixels -> D rows=co, cols=px -> coalesced f32 NCHW stores.
// Wave = 32co x 64px (2 mt x 4 nt).  8 waves = 4 rows x 2 px-halves.
// ---------------------------------------------------------------------------
__global__ __launch_bounds__(512) void conv2_mfma(
    const ushort* __restrict__ est, const ushort* __restrict__ wO2,
    const ushort* __restrict__ zp, float* __restrict__ offs) {
    __shared__ ushort lws[2][SLOTS_PAD * 8];
    const int t = threadIdx.x, lane = t & 63, wid = t >> 6;
    const int l15 = lane & 15, lg = lane >> 4;
    const int wm = wid >> 1, wn = wid & 1;     // row-in-tile, px-half
    const int b = blockIdx.x >> 5, yt = blockIdx.x & 31;
    const int y0 = yt * 4;
    const ushort* nb = est + (size_t)(b * HH) * WW * 128;

    auto stage = [&](int cc, int bf) {
        for (int s0 = wid * 64; s0 < SLOTS; s0 += 512) {
            const int s = s0 + lane;
            const int sc = (s < SLOTS) ? s : (SLOTS - 1);
            const int plane = sc / 130, px = sc % 130;
            const int r = plane >> 2, q = plane & 3;
            const int yy = y0 + r - 1, xx = px - 1;
            const ushort* g =
                ((unsigned)yy < (unsigned)HH && (unsigned)xx < (unsigned)WW)
                    ? nb + ((size_t)yy * WW + xx) * 128 + cc * 32 + q * 8
                    : zp;
            __builtin_amdgcn_global_load_lds(
                (const __attribute__((address_space(1))) void*)g,
                (__attribute__((address_space(3))) void*)(&lws[bf][s0 * 8]),
                16, 0, 0);
        }
    };

    f32x4 acc[2][4] = {};
    stage(0, 0);
    __syncthreads();
#pragma unroll
    for (int cc = 0; cc < 4; ++cc) {
        if (cc < 3) stage(cc + 1, (cc + 1) & 1);
        const ushort* buf = lws[cc & 1];
#pragma unroll
        for (int tap = 0; tap < 9; ++tap) {
            const int ky = tap / 3, kx = tap % 3;
            bf16x8 aw[2], bx[4];
#pragma unroll
            for (int mt = 0; mt < 2; ++mt)
                aw[mt] = *(const bf16x8*)&wO2[(size_t)(((cc * 9 + tap) * 4 + lg) * 32
                                                      + mt * 16 + l15) * 8];
#pragma unroll
            for (int nt = 0; nt < 4; ++nt)
                bx[nt] = *(const bf16x8*)
                    &buf[(((wm + ky) * 4 + lg) * 130
                          + wn * 64 + nt * 16 + l15 + kx) * 8];
#pragma unroll
            for (int mt = 0; mt < 2; ++mt)
#pragma unroll
                for (int nt = 0; nt < 4; ++nt)
                    acc[mt][nt] = __builtin_amdgcn_mfma_f32_16x16x32_bf16(
                        aw[mt], bx[nt], acc[mt][nt], 0, 0, 0);
        }
        __syncthreads();
    }

    const int y = y0 + wm;
    float* obp = offs + (size_t)b * 18 * HW + (size_t)y * WW;
#pragma unroll
    for (int mt = 0; mt < 2; ++mt)
#pragma unroll
        for (int j = 0; j < 4; ++j) {
            const int co = mt * 16 + lg * 4 + j;
            if (co < 18)
#pragma unroll
                for (int nt = 0; nt < 4; ++nt)
                    obp[(size_t)co * HW + wn * 64 + nt * 16 + l15] = acc[mt][nt][j];
        }
}

// ---------------------------------------------------------------------------
// Deformable conv v4: no LDS, no barriers.  Weights from global in coalesced
// [tap][h][lg][co][8] layout (4x256B segments/instr, 72KB L2-hot).  Taps in
// 3 groups of 3: batch-issue 24 gathers, then consume (cross-tap latency
// hiding without wave coupling).
// ---------------------------------------------------------------------------
__device__ inline void def_coords(const ushort* __restrict__ nb, int y, int x,
                                  int k, float dy, float dx, int chan_base,
                                  float* __restrict__ w,
                                  const ushort** __restrict__ p) {
    const int ky = k / 3 - 1, kx = k % 3 - 1;
    const float py  = (float)(y + ky) + dy;
    const float pxf = (float)(x + kx) + dx;
    const float y0f = floorf(py), x0f = floorf(pxf);
    const float wy1 = py - y0f, wx1 = pxf - x0f;
    const float wy0 = 1.f - wy1, wx0 = 1.f - wx1;
    const int y0 = (int)y0f, x0 = (int)x0f;
    const int y1 = y0 + 1, x1 = x0 + 1;
    const bool vy0 = (unsigned)y0 < (unsigned)HH;
    const bool vy1 = (unsigned)y1 < (unsigned)HH;
    const bool vx0 = (unsigned)x0 < (unsigned)WW;
    const bool vx1 = (unsigned)x1 < (unsigned)WW;
    w[0] = wy0 * wx0 * ((vy0 && vx0) ? 1.f : 0.f);
    w[1] = wy0 * wx1 * ((vy0 && vx1) ? 1.f : 0.f);
    w[2] = wy1 * wx0 * ((vy1 && vx0) ? 1.f : 0.f);
    w[3] = wy1 * wx1 * ((vy1 && vx1) ? 1.f : 0.f);
    const int y0c = min(max(y0, 0), HH - 1), y1c = min(max(y1, 0), HH - 1);
    const int x0c = min(max(x0, 0), WW - 1), x1c = min(max(x1, 0), WW - 1);
    p[0] = nb + ((size_t)y0c * WW + x0c) * 128 + chan_base;
    p[1] = nb + ((size_t)y0c * WW + x1c) * 128 + chan_base;
    p[2] = nb + ((size_t)y1c * WW + x0c) * 128 + chan_base;
    p[3] = nb + ((size_t)y1c * WW + x1c) * 128 + chan_base;
}

__global__ __launch_bounds__(256) void deform_mfma(
    const ushort* __restrict__ nhwc,   // [b][y][x][128]
    const float* __restrict__ offs,    // [b][18][H][W]
    const ushort* __restrict__ wD4,    // [9][2][4][64][8]
    float* __restrict__ out) {         // [b][64][H][W]
    const int t = threadIdx.x, lane = t & 63, wid = t >> 6;
    const int l15 = lane & 15, lg = lane >> 4;
    const int bi = blockIdx.x;
    const int xq = bi & 3, yp = (bi >> 2) & 63, b = bi >> 8;
    const int y = yp * 2 + (wid >> 1);
    const int x = xq * 32 + (wid & 1) * 16 + l15;

    const ushort* nb = nhwc + (size_t)(b * HH) * WW * 128;
    const float* ob = offs + (size_t)b * 18 * HW + (size_t)y * WW + x;
    const int cb = 64 + lg * 8;        // hr channels live at +64 in concat buf

    float dyv[9], dxv[9];
#pragma unroll
    for (int k = 0; k < 9; ++k) {
        dyv[k] = ob[(size_t)(2 * k) * HW];
        dxv[k] = ob[(size_t)(2 * k + 1) * HW];
    }

    f32x4 acc[4] = {};
#pragma unroll
    for (int g0 = 0; g0 < 9; g0 += 3) {
        float wz[3][4];
        bf16x8 gv[3][8];
        // batch-issue this group's 24 gathers (all independent, stay in flight)
#pragma unroll
        for (int u = 0; u < 3; ++u) {
            const ushort* p[4];
            def_coords(nb, y, x, g0 + u, dyv[g0 + u], dxv[g0 + u], cb, wz[u], p);
#pragma unroll
            for (int c = 0; c < 4; ++c) {
                gv[u][c]     = *(const bf16x8*)(p[c]);
                gv[u][4 + c] = *(const bf16x8*)(p[c] + 32);
            }
        }
        // consume: per tap, per channel-half: weights + blend + MFMA
#pragma unroll
        for (int u = 0; u < 3; ++u) {
            const int k = g0 + u;
#pragma unroll
            for (int h = 0; h < 2; ++h) {
                bf16x8 afr[4];
#pragma unroll
                for (int mt = 0; mt < 4; ++mt)
                    afr[mt] = *(const bf16x8*)&wD4[(size_t)(((k * 2 + h) * 4 + lg) * 64
                                                           + mt * 16 + l15) * 8];
                float s[8];
#pragma unroll
                for (int j = 0; j < 8; ++j)
                    s[j] = wz[u][0] * bf2f((ushort)gv[u][h * 4 + 0][j])
                         + wz[u][1] * bf2f((ushort)gv[u][h * 4 + 1][j])
                         + wz[u][2] * bf2f((ushort)gv[u][h * 4 + 2][j])
                         + wz[u][3] * bf2f((ushort)gv[u][h * 4 + 3][j]);
                union { unsigned u32[4]; bf16x8 v; } bf;
#pragma unroll
                for (int j2 = 0; j2 < 4; ++j2) {
                    __hip_bfloat162 hh =
                        __float22bfloat162_rn(make_float2(s[2 * j2], s[2 * j2 + 1]));
                    __builtin_memcpy(&bf.u32[j2], &hh, 4);
                }
#pragma unroll
                for (int mt = 0; mt < 4; ++mt)
                    acc[mt] = __builtin_amdgcn_mfma_f32_16x16x32_bf16(
                        afr[mt], bf.v, acc[mt], 0, 0, 0);
            }
        }
    }

#pragma unroll
    for (int mt = 0; mt < 4; ++mt)
#pragma unroll
        for (int j = 0; j < 4; ++j) {
            const int co = mt * 16 + lg * 4 + j;
            out[(((size_t)(b * CC + co)) * HH + y) * WW + x] = acc[mt][j];
        }
}

// ---------------------------------------------------------------------------
// Workspace:
//   in_nhwc  bf16  33,554,432
//   est_nhwc bf16  33,554,432
//   offs     f32    9,437,184
//   wE2      bf16     294,912
//   wO2      bf16      73,728
//   wD4      bf16      73,728
//   zpage             256 (zeroed each launch)
// total ~77 MB
// ---------------------------------------------------------------------------
extern "C" void kernel_launch(void* const* d_in, const int* in_sizes, int n_in,
                              void* d_out, int out_size, void* d_ws, size_t ws_size,
                              hipStream_t stream) {
    const float* lr    = (const float*)d_in[0];
    const float* hr    = (const float*)d_in[1];
    const float* w_est = (const float*)d_in[2];
    const float* w_off = (const float*)d_in[3];
    const float* w_def = (const float*)d_in[4];
    float* out = (float*)d_out;

    char* ws = (char*)d_ws;
    ushort* in_nhwc  = (ushort*)ws;   ws += (size_t)BB * HH * WW * 128 * 2;
    ushort* est_nhwc = (ushort*)ws;   ws += (size_t)BB * HH * WW * 128 * 2;
    float*  offs     = (float*)ws;    ws += (size_t)BB * 18 * HW * 4;
    ushort* wE2      = (ushort*)ws;   ws += (size_t)128 * 1152 * 2;
    ushort* wO2      = (ushort*)ws;   ws += (size_t)144 * 32 * 8 * 2;
    ushort* wD4      = (ushort*)ws;   ws += (size_t)9 * 4096 * 2;
    ushort* zp       = (ushort*)ws;

    hipMemsetAsync(zp, 0, 256, stream);
    pack_wE2<<<(128 * 1152 + 255) / 256, 256, 0, stream>>>(w_est, wE2);
    pack_wO2<<<(144 * 32 * 8 + 255) / 256, 256, 0, stream>>>(w_off, wO2);
    pack_wD4<<<(9 * 4096 + 255) / 256, 256, 0, stream>>>(w_def, wD4);

    to_nhwc_bf16<<<BB * HH, 256, 0, stream>>>(lr, hr, in_nhwc);

    conv1_mfma<<<BB * (HH / 4), 512, 0, stream>>>(in_nhwc, wE2, zp, est_nhwc);
    conv2_mfma<<<BB * (HH / 4), 512, 0, stream>>>(est_nhwc, wO2, zp, offs);

    deform_mfma<<<BB * HH * 2, 256, 0, stream>>>(in_nhwc, offs, wD4, out);
}

// Round 8
// 165.189 us; speedup vs baseline: 6.4541x; 1.0632x over previous
//
#include <hip/hip_runtime.h>
#include <hip/hip_bf16.h>

// DeformableConvBlock: B=8, C=64, H=W=128
#define BB 8
#define CC 64
#define C2 128
#define HH 128
#define WW 128
#define HW (HH * WW)

typedef __attribute__((ext_vector_type(8))) short bf16x8;
typedef __attribute__((ext_vector_type(4))) float f32x4;
typedef __attribute__((ext_vector_type(2))) float f32x2;
typedef __attribute__((ext_vector_type(4))) unsigned u32x4;

__device__ inline ushort f2bf(float f) {
    union { float f; unsigned u; } v; v.f = f;
    unsigned r = v.u + 0x7fff + ((v.u >> 16) & 1);   // RNE
    return (ushort)(r >> 16);
}
__device__ inline float bf2f(ushort u) {
    union { unsigned u; float f; } v; v.u = (unsigned)u << 16; return v.f;
}

// ---------------------------------------------------------------------------
// Pre-pass: concat(lr,hr) fp32 NCHW -> bf16 NHWC [b][y][x][128ci]
// ---------------------------------------------------------------------------
__global__ __launch_bounds__(256) void to_nhwc_bf16(
    const float* __restrict__ lr, const float* __restrict__ hr,
    ushort* __restrict__ dst) {
    __shared__ ushort lt[HH][136];
    const int t = threadIdx.x;
    const int b = blockIdx.x >> 7, y = blockIdx.x & 127;
    for (int ci0 = 0; ci0 < 128; ci0 += 2) {
        const int ci = ci0 + (t >> 7);
        const int x = t & 127;
        const float* s = (ci < 64) ? lr + ((size_t)(b * 64 + ci)) * HW
                                   : hr + ((size_t)(b * 64 + ci - 64)) * HW;
        lt[x][ci] = f2bf(s[y * WW + x]);
    }
    __syncthreads();
    ushort* db = dst + ((size_t)blockIdx.x) * WW * 128;
    for (int i = t; i < 128 * 16; i += 256) {
        const int px = i >> 4, q = i & 15;
        uint4 v = *(const uint4*)&lt[px][q * 8];
        *(uint4*)&db[(size_t)px * 128 + q * 8] = v;
    }
}

// ---------------------------------------------------------------------------
// Weight packs.
// conv1 wE2: [kb][128co][8], kb=(cc*9+tap)*4+lg, ci=cc*32+lg*8+c7
// conv2 wO2: [kb][32co][8], same kb; co>=18 zero-padded
// deform wD4: [tap][h][lg][64co][8], c = h*32+lg*8+c7
// ---------------------------------------------------------------------------
__global__ void pack_wE2(const float* __restrict__ w, ushort* __restrict__ o_) {
    int i = blockIdx.x * 256 + threadIdx.x;
    if (i >= 128 * 1152) return;
    int c7 = i & 7, co = (i >> 3) & 127, kb = i >> 10;
    int lg = kb & 3, ct = kb >> 2, tap = ct % 9, cc = ct / 9;
    int ci = cc * 32 + lg * 8 + c7;
    o_[i] = f2bf(w[((size_t)co * 128 + ci) * 9 + tap]);
}
__global__ void pack_wO2(const float* __restrict__ w, ushort* __restrict__ o_) {
    int i = blockIdx.x * 256 + threadIdx.x;
    if (i >= 144 * 32 * 8) return;
    int c7 = i & 7, co = (i >> 3) & 31, kb = i >> 8;
    int lg = kb & 3, ct = kb >> 2, tap = ct % 9, cc = ct / 9;
    int ci = cc * 32 + lg * 8 + c7;
    o_[i] = (co < 18) ? f2bf(w[((size_t)co * 128 + ci) * 9 + tap]) : (ushort)0;
}
__global__ void pack_wD4(const float* __restrict__ w, ushort* __restrict__ o_) {
    int i = blockIdx.x * 256 + threadIdx.x;
    if (i >= 9 * 4096) return;
    int c7 = i & 7, co = (i >> 3) & 63, lg = (i >> 9) & 3, h = (i >> 11) & 1,
        tap = i >> 12;
    int c = h * 32 + lg * 8 + c7;
    o_[i] = f2bf(w[((size_t)co * 64 + c) * 9 + tap]);
}

// ---------------------------------------------------------------------------
// conv1 v2 (unchanged): 4-row tile, 512 thr, dbuf global_load_lds staging.
// ---------------------------------------------------------------------------
#define SLOTS 3120         // 6*4*130
#define SLOTS_PAD 3136

__global__ __launch_bounds__(512) void conv1_mfma(
    const ushort* __restrict__ nhwc, const ushort* __restrict__ wE2,
    const ushort* __restrict__ zp, ushort* __restrict__ est) {
    __shared__ ushort lws[2][SLOTS_PAD * 8];   // 2 x 50,176 B
    const int t = threadIdx.x, lane = t & 63, wid = t >> 6;
    const int l15 = lane & 15, lg = lane >> 4;
    const int wm = wid >> 1, wn = wid & 1;
    const int b = blockIdx.x >> 5, yt = blockIdx.x & 31;
    const int y0 = yt * 4;
    const ushort* nb = nhwc + (size_t)(b * HH) * WW * 128;

    auto stage = [&](int cc, int bf) {
        for (int s0 = wid * 64; s0 < SLOTS; s0 += 512) {
            const int s = s0 + lane;
            const int sc = (s < SLOTS) ? s : (SLOTS - 1);
            const int plane = sc / 130, px = sc % 130;
            const int r = plane >> 2, q = plane & 3;
            const int yy = y0 + r - 1, xx = px - 1;
            const ushort* g =
                ((unsigned)yy < (unsigned)HH && (unsigned)xx < (unsigned)WW)
                    ? nb + ((size_t)yy * WW + xx) * 128 + cc * 32 + q * 8
                    : zp;
            __builtin_amdgcn_global_load_lds(
                (const __attribute__((address_space(1))) void*)g,
                (__attribute__((address_space(3))) void*)(&lws[bf][s0 * 8]),
                16, 0, 0);
        }
    };

    f32x4 acc[8][4] = {};
    stage(0, 0);
    __syncthreads();
#pragma unroll
    for (int cc = 0; cc < 4; ++cc) {
        if (cc < 3) stage(cc + 1, (cc + 1) & 1);
        const ushort* buf = lws[cc & 1];
#pragma unroll
        for (int tap = 0; tap < 9; ++tap) {
            const int ky = tap / 3, kx = tap % 3;
            bf16x8 a[8], w[4];
#pragma unroll
            for (int mt = 0; mt < 8; ++mt)
                a[mt] = *(const bf16x8*)
                    &buf[(((wm + ky) * 4 + lg) * 130 + mt * 16 + l15 + kx) * 8];
#pragma unroll
            for (int nt = 0; nt < 4; ++nt)
                w[nt] = *(const bf16x8*)&wE2[(size_t)(((cc * 9 + tap) * 4 + lg) * 128
                                                     + wn * 64 + nt * 16 + l15) * 8];
#pragma unroll
            for (int mt = 0; mt < 8; ++mt)
#pragma unroll
                for (int nt = 0; nt < 4; ++nt)
                    acc[mt][nt] = __builtin_amdgcn_mfma_f32_16x16x32_bf16(
                        a[mt], w[nt], acc[mt][nt], 0, 0, 0);
        }
        __syncthreads();
    }

    const int y = y0 + wm;
    ushort* eb = est + ((size_t)(b * HH + y)) * WW * 128;
#pragma unroll
    for (int mt = 0; mt < 8; ++mt)
#pragma unroll
        for (int nt = 0; nt < 4; ++nt)
#pragma unroll
            for (int j = 0; j < 4; ++j) {
                float r = acc[mt][nt][j];
                r = (r >= 0.f) ? r : 0.1f * r;
                eb[(size_t)(mt * 16 + lg * 4 + j) * 128
                   + wn * 64 + nt * 16 + l15] = f2bf(r);
            }
}

// ---------------------------------------------------------------------------
// conv2 v2 (unchanged): A = weights (32 co, 18 valid), B = est pixels.
// ---------------------------------------------------------------------------
__global__ __launch_bounds__(512) void conv2_mfma(
    const ushort* __restrict__ est, const ushort* __restrict__ wO2,
    const ushort* __restrict__ zp, float* __restrict__ offs) {
    __shared__ ushort lws[2][SLOTS_PAD * 8];
    const int t = threadIdx.x, lane = t & 63, wid = t >> 6;
    const int l15 = lane & 15, lg = lane >> 4;
    const int wm = wid >> 1, wn = wid & 1;
    const int b = blockIdx.x >> 5, yt = blockIdx.x & 31;
    const int y0 = yt * 4;
    const ushort* nb = est + (size_t)(b * HH) * WW * 128;

    auto stage = [&](int cc, int bf) {
        for (int s0 = wid * 64; s0 < SLOTS; s0 += 512) {
            const int s = s0 + lane;
            const int sc = (s < SLOTS) ? s : (SLOTS - 1);
            const int plane = sc / 130, px = sc % 130;
            const int r = plane >> 2, q = plane & 3;
            const int yy = y0 + r - 1, xx = px - 1;
            const ushort* g =
                ((unsigned)yy < (unsigned)HH && (unsigned)xx < (unsigned)WW)
                    ? nb + ((size_t)yy * WW + xx) * 128 + cc * 32 + q * 8
                    : zp;
            __builtin_amdgcn_global_load_lds(
                (const __attribute__((address_space(1))) void*)g,
                (__attribute__((address_space(3))) void*)(&lws[bf][s0 * 8]),
                16, 0, 0);
        }
    };

    f32x4 acc[2][4] = {};
    stage(0, 0);
    __syncthreads();
#pragma unroll
    for (int cc = 0; cc < 4; ++cc) {
        if (cc < 3) stage(cc + 1, (cc + 1) & 1);
        const ushort* buf = lws[cc & 1];
#pragma unroll
        for (int tap = 0; tap < 9; ++tap) {
            const int ky = tap / 3, kx = tap % 3;
            bf16x8 aw[2], bx[4];
#pragma unroll
            for (int mt = 0; mt < 2; ++mt)
                aw[mt] = *(const bf16x8*)&wO2[(size_t)(((cc * 9 + tap) * 4 + lg) * 32
                                                      + mt * 16 + l15) * 8];
#pragma unroll
            for (int nt = 0; nt < 4; ++nt)
                bx[nt] = *(const bf16x8*)
                    &buf[(((wm + ky) * 4 + lg) * 130
                          + wn * 64 + nt * 16 + l15 + kx) * 8];
#pragma unroll
            for (int mt = 0; mt < 2; ++mt)
#pragma unroll
                for (int nt = 0; nt < 4; ++nt)
                    acc[mt][nt] = __builtin_amdgcn_mfma_f32_16x16x32_bf16(
                        aw[mt], bx[nt], acc[mt][nt], 0, 0, 0);
        }
        __syncthreads();
    }

    const int y = y0 + wm;
    float* obp = offs + (size_t)b * 18 * HW + (size_t)y * WW;
#pragma unroll
    for (int mt = 0; mt < 2; ++mt)
#pragma unroll
        for (int j = 0; j < 4; ++j) {
            const int co = mt * 16 + lg * 4 + j;
            if (co < 18)
#pragma unroll
                for (int nt = 0; nt < 4; ++nt)
                    obp[(size_t)co * HW + wn * 64 + nt * 16 + l15] = acc[mt][nt][j];
        }
}

// ---------------------------------------------------------------------------
// Deformable conv v5: asm-pinned gather pipeline (1 tap deep), weight slice
// per tap via global_load_lds into LDS (conflict-free [h][lg][co][8] layout),
// packed-f32x2 bilinear blend.  Per iter: vmcnt(0)+sched_barrier+raw barrier,
// then issue tap-(k+1) stage+gathers, then blend+MFMA tap k.
// ---------------------------------------------------------------------------
__device__ inline void def_coords(const ushort* __restrict__ nb, int y, int x,
                                  int k, float dy, float dx, int chan_base,
                                  float* __restrict__ w,
                                  const ushort** __restrict__ p) {
    const int ky = k / 3 - 1, kx = k % 3 - 1;
    const float py  = (float)(y + ky) + dy;
    const float pxf = (float)(x + kx) + dx;
    const float y0f = floorf(py), x0f = floorf(pxf);
    const float wy1 = py - y0f, wx1 = pxf - x0f;
    const float wy0 = 1.f - wy1, wx0 = 1.f - wx1;
    const int y0 = (int)y0f, x0 = (int)x0f;
    const int y1 = y0 + 1, x1 = x0 + 1;
    const bool vy0 = (unsigned)y0 < (unsigned)HH;
    const bool vy1 = (unsigned)y1 < (unsigned)HH;
    const bool vx0 = (unsigned)x0 < (unsigned)WW;
    const bool vx1 = (unsigned)x1 < (unsigned)WW;
    w[0] = wy0 * wx0 * ((vy0 && vx0) ? 1.f : 0.f);
    w[1] = wy0 * wx1 * ((vy0 && vx1) ? 1.f : 0.f);
    w[2] = wy1 * wx0 * ((vy1 && vx0) ? 1.f : 0.f);
    w[3] = wy1 * wx1 * ((vy1 && vx1) ? 1.f : 0.f);
    const int y0c = min(max(y0, 0), HH - 1), y1c = min(max(y1, 0), HH - 1);
    const int x0c = min(max(x0, 0), WW - 1), x1c = min(max(x1, 0), WW - 1);
    p[0] = nb + ((size_t)y0c * WW + x0c) * 128 + chan_base;
    p[1] = nb + ((size_t)y0c * WW + x1c) * 128 + chan_base;
    p[2] = nb + ((size_t)y1c * WW + x0c) * 128 + chan_base;
    p[3] = nb + ((size_t)y1c * WW + x1c) * 128 + chan_base;
}

__global__ __launch_bounds__(256) void deform_mfma(
    const ushort* __restrict__ nhwc,   // [b][y][x][128]
    const float* __restrict__ offs,    // [b][18][H][W]
    const ushort* __restrict__ wD4,    // [9][2][4][64][8]
    float* __restrict__ out) {         // [b][64][H][W]
    __shared__ ushort wlds[2][4096];   // per-tap 8KB weight slice, dbuf
    const int t = threadIdx.x, lane = t & 63, wid = t >> 6;
    const int l15 = lane & 15, lg = lane >> 4;
    const int bi = blockIdx.x;
    const int xq = bi & 3, yp = (bi >> 2) & 63, b = bi >> 8;
    const int y = yp * 2 + (wid >> 1);
    const int x = xq * 32 + (wid & 1) * 16 + l15;

    const ushort* nb = nhwc + (size_t)(b * HH) * WW * 128;
    const float* ob = offs + (size_t)b * 18 * HW + (size_t)y * WW + x;
    const int cb = 64 + lg * 8;        // hr channels live at +64 in concat buf

    float dyv[9], dxv[9];
#pragma unroll
    for (int k = 0; k < 9; ++k) {
        dyv[k] = ob[(size_t)(2 * k) * HW];
        dxv[k] = ob[(size_t)(2 * k + 1) * HW];
    }

    // stage tap-k weight slice into wlds[bf]: linear, 2x16B per thread
    auto stagew = [&](int k, int bf) {
#pragma unroll
        for (int c = 0; c < 2; ++c) {
            const ushort* src = wD4 + k * 4096 + (wid * 2 + c) * 512 + lane * 8;
            __builtin_amdgcn_global_load_lds(
                (const __attribute__((address_space(1))) void*)src,
                (__attribute__((address_space(3))) void*)(&wlds[bf][(wid * 2 + c) * 512]),
                16, 0, 0);
        }
    };
    // issue 8 pinned gathers for tap k
    auto issue_g = [&](int k, u32x4* g, float* wz) {
        const ushort* p[4];
        def_coords(nb, y, x, k, dyv[k], dxv[k], cb, wz, p);
#pragma unroll
        for (int c = 0; c < 4; ++c) {
            asm volatile("global_load_dwordx4 %0, %1, off"
                         : "=v"(g[c]) : "v"(p[c]));
            asm volatile("global_load_dwordx4 %0, %1, off offset:64"
                         : "=v"(g[4 + c]) : "v"(p[c]));
        }
    };

    u32x4 gcur[8], gnxt[8];
    float wcur[4], wnxt[4];

    stagew(0, 0);
    issue_g(0, gcur, wcur);

    f32x4 acc[4] = {};
    int cur = 0;
#pragma unroll
    for (int k = 0; k < 9; ++k) {
        // wait own stage(k)+gather(k); sync waves so wlds[cur] is valid
        asm volatile("s_waitcnt vmcnt(0)" ::: "memory");
        __builtin_amdgcn_sched_barrier(0);
        __builtin_amdgcn_s_barrier();
        __builtin_amdgcn_sched_barrier(0);
        // issue next tap's stage + gathers (in flight across blend+MFMA below)
        if (k < 8) {
            stagew(k + 1, cur ^ 1);
            issue_g(k + 1, gnxt, wnxt);
        }
        // blend tap k (packed f32x2) + MFMA
#pragma unroll
        for (int h = 0; h < 2; ++h) {
            bf16x8 afr[4];
#pragma unroll
            for (int mt = 0; mt < 4; ++mt)
                afr[mt] = *(const bf16x8*)
                    &wlds[cur][(((h * 4 + lg) * 64) + mt * 16 + l15) * 8];
            union { unsigned u[4]; bf16x8 v; } bv;
#pragma unroll
            for (int q = 0; q < 4; ++q) {     // q-th u32 = channels 2q,2q+1
                f32x2 s = {0.f, 0.f};
#pragma unroll
                for (int c = 0; c < 4; ++c) {
                    const unsigned u = gcur[h * 4 + c][q];
                    f32x2 cf;
                    cf.x = __uint_as_float(u << 16);
                    cf.y = __uint_as_float(u & 0xffff0000u);
                    s.x = fmaf(wcur[c], cf.x, s.x);
                    s.y = fmaf(wcur[c], cf.y, s.y);
                }
                __hip_bfloat162 hh = __float22bfloat162_rn(make_float2(s.x, s.y));
                __builtin_memcpy(&bv.u[q], &hh, 4);
            }
#pragma unroll
            for (int mt = 0; mt < 4; ++mt)
                acc[mt] = __builtin_amdgcn_mfma_f32_16x16x32_bf16(
                    afr[mt], bv.v, acc[mt], 0, 0, 0);
        }
        // rotate ping-pong (SSA-renamed under full unroll)
#pragma unroll
        for (int c = 0; c < 8; ++c) gcur[c] = gnxt[c];
#pragma unroll
        for (int c = 0; c < 4; ++c) wcur[c] = wnxt[c];
        cur ^= 1;
    }

#pragma unroll
    for (int mt = 0; mt < 4; ++mt)
#pragma unroll
        for (int j = 0; j < 4; ++j) {
            const int co = mt * 16 + lg * 4 + j;
            out[(((size_t)(b * CC + co)) * HH + y) * WW + x] = acc[mt][j];
        }
}

// ---------------------------------------------------------------------------
// Workspace:
//   in_nhwc  bf16  33,554,432
//   est_nhwc bf16  33,554,432
//   offs     f32    9,437,184
//   wE2      bf16     294,912
//   wO2      bf16      73,728
//   wD4      bf16      73,728
//   zpage             256 (zeroed each launch)
// total ~77 MB
// ---------------------------------------------------------------------------
extern "C" void kernel_launch(void* const* d_in, const int* in_sizes, int n_in,
                              void* d_out, int out_size, void* d_ws, size_t ws_size,
                              hipStream_t stream) {
    const float* lr    = (const float*)d_in[0];
    const float* hr    = (const float*)d_in[1];
    const float* w_est = (const float*)d_in[2];
    const float* w_off = (const float*)d_in[3];
    const float* w_def = (const float*)d_in[4];
    float* out = (float*)d_out;

    char* ws = (char*)d_ws;
    ushort* in_nhwc  = (ushort*)ws;   ws += (size_t)BB * HH * WW * 128 * 2;
    ushort* est_nhwc = (ushort*)ws;   ws += (size_t)BB * HH * WW * 128 * 2;
    float*  offs     = (float*)ws;    ws += (size_t)BB * 18 * HW * 4;
    ushort* wE2      = (ushort*)ws;   ws += (size_t)128 * 1152 * 2;
    ushort* wO2      = (ushort*)ws;   ws += (size_t)144 * 32 * 8 * 2;
    ushort* wD4      = (ushort*)ws;   ws += (size_t)9 * 4096 * 2;
    ushort* zp       = (ushort*)ws;

    hipMemsetAsync(zp, 0, 256, stream);
    pack_wE2<<<(128 * 1152 + 255) / 256, 256, 0, stream>>>(w_est, wE2);
    pack_wO2<<<(144 * 32 * 8 + 255) / 256, 256, 0, stream>>>(w_off, wO2);
    pack_wD4<<<(9 * 4096 + 255) / 256, 256, 0, stream>>>(w_def, wD4);

    to_nhwc_bf16<<<BB * HH, 256, 0, stream>>>(lr, hr, in_nhwc);

    conv1_mfma<<<BB * (HH / 4), 512, 0, stream>>>(in_nhwc, wE2, zp, est_nhwc);
    conv2_mfma<<<BB * (HH / 4), 512, 0, stream>>>(est_nhwc, wO2, zp, offs);

    deform_mfma<<<BB * HH * 2, 256, 0, stream>>>(in_nhwc, offs, wD4, out);
}

// Round 11
// 164.988 us; speedup vs baseline: 6.4619x; 1.0012x over previous
//
#include <hip/hip_runtime.h>
#include <hip/hip_bf16.h>

// DeformableConvBlock: B=8, C=64, H=W=128
#define BB 8
#define CC 64
#define C2 128
#define HH 128
#define WW 128
#define HW (HH * WW)

typedef __attribute__((ext_vector_type(8))) short bf16x8;
typedef __attribute__((ext_vector_type(4))) float f32x4;
typedef __attribute__((ext_vector_type(2))) float f32x2;
typedef __attribute__((ext_vector_type(4))) unsigned u32x4;

__device__ inline ushort f2bf(float f) {
    union { float f; unsigned u; } v; v.f = f;
    unsigned r = v.u + 0x7fff + ((v.u >> 16) & 1);   // RNE
    return (ushort)(r >> 16);
}
__device__ inline float bf2f(ushort u) {
    union { unsigned u; float f; } v; v.u = (unsigned)u << 16; return v.f;
}

// ---------------------------------------------------------------------------
// Pre-pass: concat(lr,hr) fp32 NCHW -> bf16 NHWC [b][y][x][128ci]
// ---------------------------------------------------------------------------
__global__ __launch_bounds__(256) void to_nhwc_bf16(
    const float* __restrict__ lr, const float* __restrict__ hr,
    ushort* __restrict__ dst) {
    __shared__ ushort lt[HH][136];
    const int t = threadIdx.x;
    const int b = blockIdx.x >> 7, y = blockIdx.x & 127;
    for (int ci0 = 0; ci0 < 128; ci0 += 2) {
        const int ci = ci0 + (t >> 7);
        const int x = t & 127;
        const float* s = (ci < 64) ? lr + ((size_t)(b * 64 + ci)) * HW
                                   : hr + ((size_t)(b * 64 + ci - 64)) * HW;
        lt[x][ci] = f2bf(s[y * WW + x]);
    }
    __syncthreads();
    ushort* db = dst + ((size_t)blockIdx.x) * WW * 128;
    for (int i = t; i < 128 * 16; i += 256) {
        const int px = i >> 4, q = i & 15;
        uint4 v = *(const uint4*)&lt[px][q * 8];
        *(uint4*)&db[(size_t)px * 128 + q * 8] = v;
    }
}

// ---------------------------------------------------------------------------
// Weight packs.
// conv1 wE2: [kb][128co][8], kb=(cc*9+tap)*4+lg, ci=cc*32+lg*8+c7
// conv2 wO2: [kb][32co][8], same kb; co>=18 zero-padded
// deform wD4: [tap][h][lg][64co][8], c = h*32+lg*8+c7
// ---------------------------------------------------------------------------
__global__ void pack_wE2(const float* __restrict__ w, ushort* __restrict__ o_) {
    int i = blockIdx.x * 256 + threadIdx.x;
    if (i >= 128 * 1152) return;
    int c7 = i & 7, co = (i >> 3) & 127, kb = i >> 10;
    int lg = kb & 3, ct = kb >> 2, tap = ct % 9, cc = ct / 9;
    int ci = cc * 32 + lg * 8 + c7;
    o_[i] = f2bf(w[((size_t)co * 128 + ci) * 9 + tap]);
}
__global__ void pack_wO2(const float* __restrict__ w, ushort* __restrict__ o_) {
    int i = blockIdx.x * 256 + threadIdx.x;
    if (i >= 144 * 32 * 8) return;
    int c7 = i & 7, co = (i >> 3) & 31, kb = i >> 8;
    int lg = kb & 3, ct = kb >> 2, tap = ct % 9, cc = ct / 9;
    int ci = cc * 32 + lg * 8 + c7;
    o_[i] = (co < 18) ? f2bf(w[((size_t)co * 128 + ci) * 9 + tap]) : (ushort)0;
}
__global__ void pack_wD4(const float* __restrict__ w, ushort* __restrict__ o_) {
    int i = blockIdx.x * 256 + threadIdx.x;
    if (i >= 9 * 4096) return;
    int c7 = i & 7, co = (i >> 3) & 63, lg = (i >> 9) & 3, h = (i >> 11) & 1,
        tap = i >> 12;
    int c = h * 32 + lg * 8 + c7;
    o_[i] = f2bf(w[((size_t)co * 64 + c) * 9 + tap]);
}

// ---------------------------------------------------------------------------
// conv1 v2 (unchanged): 4-row tile, 512 thr, dbuf global_load_lds staging.
// ---------------------------------------------------------------------------
#define SLOTS 3120         // 6*4*130
#define SLOTS_PAD 3136

__global__ __launch_bounds__(512) void conv1_mfma(
    const ushort* __restrict__ nhwc, const ushort* __restrict__ wE2,
    const ushort* __restrict__ zp, ushort* __restrict__ est) {
    __shared__ ushort lws[2][SLOTS_PAD * 8];   // 2 x 50,176 B
    const int t = threadIdx.x, lane = t & 63, wid = t >> 6;
    const int l15 = lane & 15, lg = lane >> 4;
    const int wm = wid >> 1, wn = wid & 1;
    const int b = blockIdx.x >> 5, yt = blockIdx.x & 31;
    const int y0 = yt * 4;
    const ushort* nb = nhwc + (size_t)(b * HH) * WW * 128;

    auto stage = [&](int cc, int bf) {
        for (int s0 = wid * 64; s0 < SLOTS; s0 += 512) {
            const int s = s0 + lane;
            const int sc = (s < SLOTS) ? s : (SLOTS - 1);
            const int plane = sc / 130, px = sc % 130;
            const int r = plane >> 2, q = plane & 3;
            const int yy = y0 + r - 1, xx = px - 1;
            const ushort* g =
                ((unsigned)yy < (unsigned)HH && (unsigned)xx < (unsigned)WW)
                    ? nb + ((size_t)yy * WW + xx) * 128 + cc * 32 + q * 8
                    : zp;
            __builtin_amdgcn_global_load_lds(
                (const __attribute__((address_space(1))) void*)g,
                (__attribute__((address_space(3))) void*)(&lws[bf][s0 * 8]),
                16, 0, 0);
        }
    };

    f32x4 acc[8][4] = {};
    stage(0, 0);
    __syncthreads();
#pragma unroll
    for (int cc = 0; cc < 4; ++cc) {
        if (cc < 3) stage(cc + 1, (cc + 1) & 1);
        const ushort* buf = lws[cc & 1];
#pragma unroll
        for (int tap = 0; tap < 9; ++tap) {
            const int ky = tap / 3, kx = tap % 3;
            bf16x8 a[8], w[4];
#pragma unroll
            for (int mt = 0; mt < 8; ++mt)
                a[mt] = *(const bf16x8*)
                    &buf[(((wm + ky) * 4 + lg) * 130 + mt * 16 + l15 + kx) * 8];
#pragma unroll
            for (int nt = 0; nt < 4; ++nt)
                w[nt] = *(const bf16x8*)&wE2[(size_t)(((cc * 9 + tap) * 4 + lg) * 128
                                                     + wn * 64 + nt * 16 + l15) * 8];
#pragma unroll
            for (int mt = 0; mt < 8; ++mt)
#pragma unroll
                for (int nt = 0; nt < 4; ++nt)
                    acc[mt][nt] = __builtin_amdgcn_mfma_f32_16x16x32_bf16(
                        a[mt], w[nt], acc[mt][nt], 0, 0, 0);
        }
        __syncthreads();
    }

    const int y = y0 + wm;
    ushort* eb = est + ((size_t)(b * HH + y)) * WW * 128;
#pragma unroll
    for (int mt = 0; mt < 8; ++mt)
#pragma unroll
        for (int nt = 0; nt < 4; ++nt)
#pragma unroll
            for (int j = 0; j < 4; ++j) {
                float r = acc[mt][nt][j];
                r = (r >= 0.f) ? r : 0.1f * r;
                eb[(size_t)(mt * 16 + lg * 4 + j) * 128
                   + wn * 64 + nt * 16 + l15] = f2bf(r);
            }
}

// ---------------------------------------------------------------------------
// conv2 v2 (unchanged): A = weights (32 co, 18 valid), B = est pixels.
// ---------------------------------------------------------------------------
__global__ __launch_bounds__(512) void conv2_mfma(
    const ushort* __restrict__ est, const ushort* __restrict__ wO2,
    const ushort* __restrict__ zp, float* __restrict__ offs) {
    __shared__ ushort lws[2][SLOTS_PAD * 8];
    const int t = threadIdx.x, lane = t & 63, wid = t >> 6;
    const int l15 = lane & 15, lg = lane >> 4;
    const int wm = wid >> 1, wn = wid & 1;
    const int b = blockIdx.x >> 5, yt = blockIdx.x & 31;
    const int y0 = yt * 4;
    const ushort* nb = est + (size_t)(b * HH) * WW * 128;

    auto stage = [&](int cc, int bf) {
        for (int s0 = wid * 64; s0 < SLOTS; s0 += 512) {
            const int s = s0 + lane;
            const int sc = (s < SLOTS) ? s : (SLOTS - 1);
            const int plane = sc / 130, px = sc % 130;
            const int r = plane >> 2, q = plane & 3;
            const int yy = y0 + r - 1, xx = px - 1;
            const ushort* g =
                ((unsigned)yy < (unsigned)HH && (unsigned)xx < (unsigned)WW)
                    ? nb + ((size_t)yy * WW + xx) * 128 + cc * 32 + q * 8
                    : zp;
            __builtin_amdgcn_global_load_lds(
                (const __attribute__((address_space(1))) void*)g,
                (__attribute__((address_space(3))) void*)(&lws[bf][s0 * 8]),
                16, 0, 0);
        }
    };

    f32x4 acc[2][4] = {};
    stage(0, 0);
    __syncthreads();
#pragma unroll
    for (int cc = 0; cc < 4; ++cc) {
        if (cc < 3) stage(cc + 1, (cc + 1) & 1);
        const ushort* buf = lws[cc & 1];
#pragma unroll
        for (int tap = 0; tap < 9; ++tap) {
            const int ky = tap / 3, kx = tap % 3;
            bf16x8 aw[2], bx[4];
#pragma unroll
            for (int mt = 0; mt < 2; ++mt)
                aw[mt] = *(const bf16x8*)&wO2[(size_t)(((cc * 9 + tap) * 4 + lg) * 32
                                                      + mt * 16 + l15) * 8];
#pragma unroll
            for (int nt = 0; nt < 4; ++nt)
                bx[nt] = *(const bf16x8*)
                    &buf[(((wm + ky) * 4 + lg) * 130
                          + wn * 64 + nt * 16 + l15 + kx) * 8];
#pragma unroll
            for (int mt = 0; mt < 2; ++mt)
#pragma unroll
                for (int nt = 0; nt < 4; ++nt)
                    acc[mt][nt] = __builtin_amdgcn_mfma_f32_16x16x32_bf16(
                        aw[mt], bx[nt], acc[mt][nt], 0, 0, 0);
        }
        __syncthreads();
    }

    const int y = y0 + wm;
    float* obp = offs + (size_t)b * 18 * HW + (size_t)y * WW;
#pragma unroll
    for (int mt = 0; mt < 2; ++mt)
#pragma unroll
        for (int j = 0; j < 4; ++j) {
            const int co = mt * 16 + lg * 4 + j;
            if (co < 18)
#pragma unroll
                for (int nt = 0; nt < 4; ++nt)
                    obp[(size_t)co * HW + wn * 64 + nt * 16 + l15] = acc[mt][nt][j];
        }
}

// ---------------------------------------------------------------------------
// Deformable conv v8 = r8's PROVEN loop shape (asm gathers, full-drain
// vmcnt(0) per tap, rotate-after-blend) with two changes:
//   - ALL 9 taps' weights staged to LDS once in the prologue (72 KB)
//     -> no in-loop staging, no in-loop s_barrier: waves free-run.
//   - 512-thread blocks (8 waves = 2 rows x 4 xquads) -> 16 waves/CU.
// ---------------------------------------------------------------------------
__device__ inline void def_coords(const ushort* __restrict__ nb, int y, int x,
                                  int k, float dy, float dx, int chan_base,
                                  float* __restrict__ w,
                                  const ushort** __restrict__ p) {
    const int ky = k / 3 - 1, kx = k % 3 - 1;
    const float py  = (float)(y + ky) + dy;
    const float pxf = (float)(x + kx) + dx;
    const float y0f = floorf(py), x0f = floorf(pxf);
    const float wy1 = py - y0f, wx1 = pxf - x0f;
    const float wy0 = 1.f - wy1, wx0 = 1.f - wx1;
    const int y0 = (int)y0f, x0 = (int)x0f;
    const int y1 = y0 + 1, x1 = x0 + 1;
    const bool vy0 = (unsigned)y0 < (unsigned)HH;
    const bool vy1 = (unsigned)y1 < (unsigned)HH;
    const bool vx0 = (unsigned)x0 < (unsigned)WW;
    const bool vx1 = (unsigned)x1 < (unsigned)WW;
    w[0] = wy0 * wx0 * ((vy0 && vx0) ? 1.f : 0.f);
    w[1] = wy0 * wx1 * ((vy0 && vx1) ? 1.f : 0.f);
    w[2] = wy1 * wx0 * ((vy1 && vx0) ? 1.f : 0.f);
    w[3] = wy1 * wx1 * ((vy1 && vx1) ? 1.f : 0.f);
    const int y0c = min(max(y0, 0), HH - 1), y1c = min(max(y1, 0), HH - 1);
    const int x0c = min(max(x0, 0), WW - 1), x1c = min(max(x1, 0), WW - 1);
    p[0] = nb + ((size_t)y0c * WW + x0c) * 128 + chan_base;
    p[1] = nb + ((size_t)y0c * WW + x1c) * 128 + chan_base;
    p[2] = nb + ((size_t)y1c * WW + x0c) * 128 + chan_base;
    p[3] = nb + ((size_t)y1c * WW + x1c) * 128 + chan_base;
}

__global__ __launch_bounds__(512) void deform_mfma(
    const ushort* __restrict__ nhwc,   // [b][y][x][128]
    const float* __restrict__ offs,    // [b][18][H][W]
    const ushort* __restrict__ wD4,    // [9][2][4][64][8]
    float* __restrict__ out) {         // [b][64][H][W]
    __shared__ ushort wlds[9 * 4096];  // 72 KB: ALL taps' weights
    const int t = threadIdx.x, lane = t & 63, wid = t >> 6;
    const int l15 = lane & 15, lg = lane >> 4;
    const int bi = blockIdx.x;
    const int xh = bi & 1, yp = (bi >> 1) & 63, b = bi >> 7;
    const int y = yp * 2 + (wid >> 2);
    const int x = xh * 64 + (wid & 3) * 16 + l15;

    const ushort* nb = nhwc + (size_t)(b * HH) * WW * 128;
    const float* ob = offs + (size_t)b * 18 * HW + (size_t)y * WW + x;
    const int cb = 64 + lg * 8;        // hr channels live at +64 in concat buf

    // prologue: stage ALL taps' weights (9 x 512 thr x 16 B = 73,728 B)
#pragma unroll
    for (int i = 0; i < 9; ++i) {
        const ushort* src = wD4 + i * 4096 + (wid * 64 + lane) * 8;
        __builtin_amdgcn_global_load_lds(
            (const __attribute__((address_space(1))) void*)src,
            (__attribute__((address_space(3))) void*)(&wlds[i * 4096 + wid * 512]),
            16, 0, 0);
    }

    // preload all 18 offset scalars
    float dyv[9], dxv[9];
#pragma unroll
    for (int k = 0; k < 9; ++k) {
        dyv[k] = ob[(size_t)(2 * k) * HW];
        dxv[k] = ob[(size_t)(2 * k + 1) * HW];
    }
    __syncthreads();   // weights resident (full drain); ONLY barrier

    auto issue_g = [&](int k, u32x4* g, float* wz) {
        const ushort* p[4];
        def_coords(nb, y, x, k, dyv[k], dxv[k], cb, wz, p);
#pragma unroll
        for (int c = 0; c < 4; ++c) {
            asm volatile("global_load_dwordx4 %0, %1, off"
                         : "=v"(g[c]) : "v"(p[c]));
            asm volatile("global_load_dwordx4 %0, %1, off offset:64"
                         : "=v"(g[4 + c]) : "v"(p[c]));
        }
    };

    u32x4 gcur[8], gnxt[8];
    float wcur[4], wnxt[4];
    issue_g(0, gcur, wcur);

    f32x4 acc[4] = {};
#pragma unroll
    for (int k = 0; k < 9; ++k) {
        // full drain: tap-k's gathers are architecturally settled here
        asm volatile("s_waitcnt vmcnt(0)" ::: "memory");
        __builtin_amdgcn_sched_barrier(0);
        // issue next tap's gathers (in flight across blend+MFMA below)
        if (k < 8) issue_g(k + 1, gnxt, wnxt);
        // blend tap k (packed f32x2) + MFMA
#pragma unroll
        for (int h = 0; h < 2; ++h) {
            bf16x8 afr[4];
#pragma unroll
            for (int mt = 0; mt < 4; ++mt)
                afr[mt] = *(const bf16x8*)
                    &wlds[(size_t)(((k * 2 + h) * 4 + lg) * 64 + mt * 16 + l15) * 8];
            union { unsigned u[4]; bf16x8 v; } bv;
#pragma unroll
            for (int q = 0; q < 4; ++q) {     // q-th u32 = channels 2q,2q+1
                f32x2 s = {0.f, 0.f};
#pragma unroll
                for (int c = 0; c < 4; ++c) {
                    const unsigned u = gcur[h * 4 + c][q];
                    f32x2 cf;
                    cf.x = __uint_as_float(u << 16);
                    cf.y = __uint_as_float(u & 0xffff0000u);
                    s.x = fmaf(wcur[c], cf.x, s.x);
                    s.y = fmaf(wcur[c], cf.y, s.y);
                }
                __hip_bfloat162 hh = __float22bfloat162_rn(make_float2(s.x, s.y));
                __builtin_memcpy(&bv.u[q], &hh, 4);
            }
#pragma unroll
            for (int mt = 0; mt < 4; ++mt)
                acc[mt] = __builtin_amdgcn_mfma_f32_16x16x32_bf16(
                    afr[mt], bv.v, acc[mt], 0, 0, 0);
        }
        // rotate ping-pong (renamed away under full unroll; proven in r8)
#pragma unroll
        for (int c = 0; c < 8; ++c) gcur[c] = gnxt[c];
#pragma unroll
        for (int c = 0; c < 4; ++c) wcur[c] = wnxt[c];
    }

#pragma unroll
    for (int mt = 0; mt < 4; ++mt)
#pragma unroll
        for (int j = 0; j < 4; ++j) {
            const int co = mt * 16 + lg * 4 + j;
            out[(((size_t)(b * CC + co)) * HH + y) * WW + x] = acc[mt][j];
        }
}

// ---------------------------------------------------------------------------
// Workspace:
//   in_nhwc  bf16  33,554,432
//   est_nhwc bf16  33,554,432
//   offs     f32    9,437,184
//   wE2      bf16     294,912
//   wO2      bf16      73,728
//   wD4      bf16      73,728
//   zpage             256 (zeroed each launch)
// total ~77 MB
// ---------------------------------------------------------------------------
extern "C" void kernel_launch(void* const* d_in, const int* in_sizes, int n_in,
                              void* d_out, int out_size, void* d_ws, size_t ws_size,
                              hipStream_t stream) {
    const float* lr    = (const float*)d_in[0];
    const float* hr    = (const float*)d_in[1];
    const float* w_est = (const float*)d_in[2];
    const float* w_off = (const float*)d_in[3];
    const float* w_def = (const float*)d_in[4];
    float* out = (float*)d_out;

    char* ws = (char*)d_ws;
    ushort* in_nhwc  = (ushort*)ws;   ws += (size_t)BB * HH * WW * 128 * 2;
    ushort* est_nhwc = (ushort*)ws;   ws += (size_t)BB * HH * WW * 128 * 2;
    float*  offs     = (float*)ws;    ws += (size_t)BB * 18 * HW * 4;
    ushort* wE2      = (ushort*)ws;   ws += (size_t)128 * 1152 * 2;
    ushort* wO2      = (ushort*)ws;   ws += (size_t)144 * 32 * 8 * 2;
    ushort* wD4      = (ushort*)ws;   ws += (size_t)9 * 4096 * 2;
    ushort* zp       = (ushort*)ws;

    hipMemsetAsync(zp, 0, 256, stream);
    pack_wE2<<<(128 * 1152 + 255) / 256, 256, 0, stream>>>(w_est, wE2);
    pack_wO2<<<(144 * 32 * 8 + 255) / 256, 256, 0, stream>>>(w_off, wO2);
    pack_wD4<<<(9 * 4096 + 255) / 256, 256, 0, stream>>>(w_def, wD4);

    to_nhwc_bf16<<<BB * HH, 256, 0, stream>>>(lr, hr, in_nhwc);

    conv1_mfma<<<BB * (HH / 4), 512, 0, stream>>>(in_nhwc, wE2, zp, est_nhwc);
    conv2_mfma<<<BB * (HH / 4), 512, 0, stream>>>(est_nhwc, wO2, zp, offs);

    deform_mfma<<<BB * HH, 512, 0, stream>>>(in_nhwc, offs, wD4, out);
}

// Round 12
// 137.398 us; speedup vs baseline: 7.7595x; 1.2008x over previous
//
#include <hip/hip_runtime.h>
#include <hip/hip_bf16.h>

// DeformableConvBlock: B=8, C=64, H=W=128
#define BB 8
#define CC 64
#define C2 128
#define HH 128
#define WW 128
#define HW (HH * WW)

typedef __attribute__((ext_vector_type(8))) short bf16x8;
typedef __attribute__((ext_vector_type(4))) float f32x4;
typedef __attribute__((ext_vector_type(2))) float f32x2;
typedef __attribute__((ext_vector_type(4))) unsigned u32x4;

__device__ inline ushort f2bf(float f) {
    union { float f; unsigned u; } v; v.f = f;
    unsigned r = v.u + 0x7fff + ((v.u >> 16) & 1);   // RNE
    return (ushort)(r >> 16);
}
__device__ inline float bf2f(ushort u) {
    union { unsigned u; float f; } v; v.u = (unsigned)u << 16; return v.f;
}

// ---------------------------------------------------------------------------
// Pre-pass: concat(lr,hr) fp32 NCHW -> bf16 NHWC [b][y][x][128ci]
// ---------------------------------------------------------------------------
__global__ __launch_bounds__(256) void to_nhwc_bf16(
    const float* __restrict__ lr, const float* __restrict__ hr,
    ushort* __restrict__ dst) {
    __shared__ ushort lt[HH][136];
    const int t = threadIdx.x;
    const int b = blockIdx.x >> 7, y = blockIdx.x & 127;
    for (int ci0 = 0; ci0 < 128; ci0 += 2) {
        const int ci = ci0 + (t >> 7);
        const int x = t & 127;
        const float* s = (ci < 64) ? lr + ((size_t)(b * 64 + ci)) * HW
                                   : hr + ((size_t)(b * 64 + ci - 64)) * HW;
        lt[x][ci] = f2bf(s[y * WW + x]);
    }
    __syncthreads();
    ushort* db = dst + ((size_t)blockIdx.x) * WW * 128;
    for (int i = t; i < 128 * 16; i += 256) {
        const int px = i >> 4, q = i & 15;
        uint4 v = *(const uint4*)&lt[px][q * 8];
        *(uint4*)&db[(size_t)px * 128 + q * 8] = v;
    }
}

// ---------------------------------------------------------------------------
// Weight packs.
// conv1 wE2: [kb][128co][8], kb=(cc*9+tap)*4+lg, ci=cc*32+lg*8+c7
// conv2 wO2: [kb][32co][8], same kb; co>=18 zero-padded
// deform wD4: [tap][h][lg][64co][8], c = h*32+lg*8+c7
// ---------------------------------------------------------------------------
__global__ void pack_wE2(const float* __restrict__ w, ushort* __restrict__ o_) {
    int i = blockIdx.x * 256 + threadIdx.x;
    if (i >= 128 * 1152) return;
    int c7 = i & 7, co = (i >> 3) & 127, kb = i >> 10;
    int lg = kb & 3, ct = kb >> 2, tap = ct % 9, cc = ct / 9;
    int ci = cc * 32 + lg * 8 + c7;
    o_[i] = f2bf(w[((size_t)co * 128 + ci) * 9 + tap]);
}
__global__ void pack_wO2(const float* __restrict__ w, ushort* __restrict__ o_) {
    int i = blockIdx.x * 256 + threadIdx.x;
    if (i >= 144 * 32 * 8) return;
    int c7 = i & 7, co = (i >> 3) & 31, kb = i >> 8;
    int lg = kb & 3, ct = kb >> 2, tap = ct % 9, cc = ct / 9;
    int ci = cc * 32 + lg * 8 + c7;
    o_[i] = (co < 18) ? f2bf(w[((size_t)co * 128 + ci) * 9 + tap]) : (ushort)0;
}
__global__ void pack_wD4(const float* __restrict__ w, ushort* __restrict__ o_) {
    int i = blockIdx.x * 256 + threadIdx.x;
    if (i >= 9 * 4096) return;
    int c7 = i & 7, co = (i >> 3) & 63, lg = (i >> 9) & 3, h = (i >> 11) & 1,
        tap = i >> 12;
    int c = h * 32 + lg * 8 + c7;
    o_[i] = f2bf(w[((size_t)co * 64 + c) * 9 + tap]);
}

// ---------------------------------------------------------------------------
// conv1 v2 (unchanged): 4-row tile, 512 thr, dbuf global_load_lds staging.
// ---------------------------------------------------------------------------
#define SLOTS 3120         // 6*4*130
#define SLOTS_PAD 3136

__global__ __launch_bounds__(512) void conv1_mfma(
    const ushort* __restrict__ nhwc, const ushort* __restrict__ wE2,
    const ushort* __restrict__ zp, ushort* __restrict__ est) {
    __shared__ ushort lws[2][SLOTS_PAD * 8];   // 2 x 50,176 B
    const int t = threadIdx.x, lane = t & 63, wid = t >> 6;
    const int l15 = lane & 15, lg = lane >> 4;
    const int wm = wid >> 1, wn = wid & 1;
    const int b = blockIdx.x >> 5, yt = blockIdx.x & 31;
    const int y0 = yt * 4;
    const ushort* nb = nhwc + (size_t)(b * HH) * WW * 128;

    auto stage = [&](int cc, int bf) {
        for (int s0 = wid * 64; s0 < SLOTS; s0 += 512) {
            const int s = s0 + lane;
            const int sc = (s < SLOTS) ? s : (SLOTS - 1);
            const int plane = sc / 130, px = sc % 130;
            const int r = plane >> 2, q = plane & 3;
            const int yy = y0 + r - 1, xx = px - 1;
            const ushort* g =
                ((unsigned)yy < (unsigned)HH && (unsigned)xx < (unsigned)WW)
                    ? nb + ((size_t)yy * WW + xx) * 128 + cc * 32 + q * 8
                    : zp;
            __builtin_amdgcn_global_load_lds(
                (const __attribute__((address_space(1))) void*)g,
                (__attribute__((address_space(3))) void*)(&lws[bf][s0 * 8]),
                16, 0, 0);
        }
    };

    f32x4 acc[8][4] = {};
    stage(0, 0);
    __syncthreads();
#pragma unroll
    for (int cc = 0; cc < 4; ++cc) {
        if (cc < 3) stage(cc + 1, (cc + 1) & 1);
        const ushort* buf = lws[cc & 1];
#pragma unroll
        for (int tap = 0; tap < 9; ++tap) {
            const int ky = tap / 3, kx = tap % 3;
            bf16x8 a[8], w[4];
#pragma unroll
            for (int mt = 0; mt < 8; ++mt)
                a[mt] = *(const bf16x8*)
                    &buf[(((wm + ky) * 4 + lg) * 130 + mt * 16 + l15 + kx) * 8];
#pragma unroll
            for (int nt = 0; nt < 4; ++nt)
                w[nt] = *(const bf16x8*)&wE2[(size_t)(((cc * 9 + tap) * 4 + lg) * 128
                                                     + wn * 64 + nt * 16 + l15) * 8];
#pragma unroll
            for (int mt = 0; mt < 8; ++mt)
#pragma unroll
                for (int nt = 0; nt < 4; ++nt)
                    acc[mt][nt] = __builtin_amdgcn_mfma_f32_16x16x32_bf16(
                        a[mt], w[nt], acc[mt][nt], 0, 0, 0);
        }
        __syncthreads();
    }

    const int y = y0 + wm;
    ushort* eb = est + ((size_t)(b * HH + y)) * WW * 128;
#pragma unroll
    for (int mt = 0; mt < 8; ++mt)
#pragma unroll
        for (int nt = 0; nt < 4; ++nt)
#pragma unroll
            for (int j = 0; j < 4; ++j) {
                float r = acc[mt][nt][j];
                r = (r >= 0.f) ? r : 0.1f * r;
                eb[(size_t)(mt * 16 + lg * 4 + j) * 128
                   + wn * 64 + nt * 16 + l15] = f2bf(r);
            }
}

// ---------------------------------------------------------------------------
// conv2 v2 (unchanged): A = weights (32 co, 18 valid), B = est pixels.
// ---------------------------------------------------------------------------
__global__ __launch_bounds__(512) void conv2_mfma(
    const ushort* __restrict__ est, const ushort* __restrict__ wO2,
    const ushort* __restrict__ zp, float* __restrict__ offs) {
    __shared__ ushort lws[2][SLOTS_PAD * 8];
    const int t = threadIdx.x, lane = t & 63, wid = t >> 6;
    const int l15 = lane & 15, lg = lane >> 4;
    const int wm = wid >> 1, wn = wid & 1;
    const int b = blockIdx.x >> 5, yt = blockIdx.x & 31;
    const int y0 = yt * 4;
    const ushort* nb = est + (size_t)(b * HH) * WW * 128;

    auto stage = [&](int cc, int bf) {
        for (int s0 = wid * 64; s0 < SLOTS; s0 += 512) {
            const int s = s0 + lane;
            const int sc = (s < SLOTS) ? s : (SLOTS - 1);
            const int plane = sc / 130, px = sc % 130;
            const int r = plane >> 2, q = plane & 3;
            const int yy = y0 + r - 1, xx = px - 1;
            const ushort* g =
                ((unsigned)yy < (unsigned)HH && (unsigned)xx < (unsigned)WW)
                    ? nb + ((size_t)yy * WW + xx) * 128 + cc * 32 + q * 8
                    : zp;
            __builtin_amdgcn_global_load_lds(
                (const __attribute__((address_space(1))) void*)g,
                (__attribute__((address_space(3))) void*)(&lws[bf][s0 * 8]),
                16, 0, 0);
        }
    };

    f32x4 acc[2][4] = {};
    stage(0, 0);
    __syncthreads();
#pragma unroll
    for (int cc = 0; cc < 4; ++cc) {
        if (cc < 3) stage(cc + 1, (cc + 1) & 1);
        const ushort* buf = lws[cc & 1];
#pragma unroll
        for (int tap = 0; tap < 9; ++tap) {
            const int ky = tap / 3, kx = tap % 3;
            bf16x8 aw[2], bx[4];
#pragma unroll
            for (int mt = 0; mt < 2; ++mt)
                aw[mt] = *(const bf16x8*)&wO2[(size_t)(((cc * 9 + tap) * 4 + lg) * 32
                                                      + mt * 16 + l15) * 8];
#pragma unroll
            for (int nt = 0; nt < 4; ++nt)
                bx[nt] = *(const bf16x8*)
                    &buf[(((wm + ky) * 4 + lg) * 130
                          + wn * 64 + nt * 16 + l15 + kx) * 8];
#pragma unroll
            for (int mt = 0; mt < 2; ++mt)
#pragma unroll
                for (int nt = 0; nt < 4; ++nt)
                    acc[mt][nt] = __builtin_amdgcn_mfma_f32_16x16x32_bf16(
                        aw[mt], bx[nt], acc[mt][nt], 0, 0, 0);
        }
        __syncthreads();
    }

    const int y = y0 + wm;
    float* obp = offs + (size_t)b * 18 * HW + (size_t)y * WW;
#pragma unroll
    for (int mt = 0; mt < 2; ++mt)
#pragma unroll
        for (int j = 0; j < 4; ++j) {
            const int co = mt * 16 + lg * 4 + j;
            if (co < 18)
#pragma unroll
                for (int nt = 0; nt < 4; ++nt)
                    obp[(size_t)co * HW + wn * 64 + nt * 16 + l15] = acc[mt][nt][j];
        }
}

// ---------------------------------------------------------------------------
// Deformable conv v9 = r11 structure with PIXEL-MAJOR gather mapping:
// load phase lanes = (pg=lane>>2, q=lane&3): the 4 ADJACENT lanes of one
// pixel read contiguous 64 B per corner-half -> TA line-merge (16 lines/instr
// instead of 64 lane-transactions).  Blend runs in load mapping; 8 __shfl
// per tap (src lane = l15*4+lg) re-layouts packed bf16 into the MFMA B-frag.
// ---------------------------------------------------------------------------
__device__ inline void def_coords(const ushort* __restrict__ nb, int y, int x,
                                  int k, float dy, float dx, int chan_base,
                                  float* __restrict__ w,
                                  const ushort** __restrict__ p) {
    const int ky = k / 3 - 1, kx = k % 3 - 1;
    const float py  = (float)(y + ky) + dy;
    const float pxf = (float)(x + kx) + dx;
    const float y0f = floorf(py), x0f = floorf(pxf);
    const float wy1 = py - y0f, wx1 = pxf - x0f;
    const float wy0 = 1.f - wy1, wx0 = 1.f - wx1;
    const int y0 = (int)y0f, x0 = (int)x0f;
    const int y1 = y0 + 1, x1 = x0 + 1;
    const bool vy0 = (unsigned)y0 < (unsigned)HH;
    const bool vy1 = (unsigned)y1 < (unsigned)HH;
    const bool vx0 = (unsigned)x0 < (unsigned)WW;
    const bool vx1 = (unsigned)x1 < (unsigned)WW;
    w[0] = wy0 * wx0 * ((vy0 && vx0) ? 1.f : 0.f);
    w[1] = wy0 * wx1 * ((vy0 && vx1) ? 1.f : 0.f);
    w[2] = wy1 * wx0 * ((vy1 && vx0) ? 1.f : 0.f);
    w[3] = wy1 * wx1 * ((vy1 && vx1) ? 1.f : 0.f);
    const int y0c = min(max(y0, 0), HH - 1), y1c = min(max(y1, 0), HH - 1);
    const int x0c = min(max(x0, 0), WW - 1), x1c = min(max(x1, 0), WW - 1);
    p[0] = nb + ((size_t)y0c * WW + x0c) * 128 + chan_base;
    p[1] = nb + ((size_t)y0c * WW + x1c) * 128 + chan_base;
    p[2] = nb + ((size_t)y1c * WW + x0c) * 128 + chan_base;
    p[3] = nb + ((size_t)y1c * WW + x1c) * 128 + chan_base;
}

__global__ __launch_bounds__(512) void deform_mfma(
    const ushort* __restrict__ nhwc,   // [b][y][x][128]
    const float* __restrict__ offs,    // [b][18][H][W]
    const ushort* __restrict__ wD4,    // [9][2][4][64][8]
    float* __restrict__ out) {         // [b][64][H][W]
    __shared__ ushort wlds[9 * 4096];  // 72 KB: ALL taps' weights
    const int t = threadIdx.x, lane = t & 63, wid = t >> 6;
    const int l15 = lane & 15, lg = lane >> 4;
    const int pg = lane >> 2, q = lane & 3;      // load-phase mapping
    const int bi = blockIdx.x;
    const int xh = bi & 1, yp = (bi >> 1) & 63, b = bi >> 7;
    const int y  = yp * 2 + (wid >> 2);
    const int xo = xh * 64 + (wid & 3) * 16 + l15;   // output pixel (MFMA col)
    const int xl = xh * 64 + (wid & 3) * 16 + pg;    // load-phase pixel

    const ushort* nb = nhwc + (size_t)(b * HH) * WW * 128;
    const float* obl = offs + (size_t)b * 18 * HW + (size_t)y * WW + xl;
    const int cbl = 64 + q * 8;       // hr channels at +64; this lane's octet
    const int shfl_src = (l15 << 2) | lg;   // where my MFMA octet was blended

    // prologue: stage ALL taps' weights (9 x 512 thr x 16 B = 73,728 B)
#pragma unroll
    for (int i = 0; i < 9; ++i) {
        const ushort* src = wD4 + i * 4096 + (wid * 64 + lane) * 8;
        __builtin_amdgcn_global_load_lds(
            (const __attribute__((address_space(1))) void*)src,
            (__attribute__((address_space(3))) void*)(&wlds[i * 4096 + wid * 512]),
            16, 0, 0);
    }

    // preload all 18 offset scalars for the LOAD-phase pixel
    float dyv[9], dxv[9];
#pragma unroll
    for (int k = 0; k < 9; ++k) {
        dyv[k] = obl[(size_t)(2 * k) * HW];
        dxv[k] = obl[(size_t)(2 * k + 1) * HW];
    }
    __syncthreads();   // weights resident (full drain); ONLY barrier

    // issue 8 pinned gathers for tap k: 4 corners x {octet q, octet q+4}.
    // Adjacent lanes (q=0..3, same pg) read contiguous 64 B -> line-merged.
    auto issue_g = [&](int k, u32x4* g, float* wz) {
        const ushort* p[4];
        def_coords(nb, y, xl, k, dyv[k], dxv[k], cbl, wz, p);
#pragma unroll
        for (int c = 0; c < 4; ++c) {
            asm volatile("global_load_dwordx4 %0, %1, off"
                         : "=v"(g[c]) : "v"(p[c]));
            asm volatile("global_load_dwordx4 %0, %1, off offset:64"
                         : "=v"(g[4 + c]) : "v"(p[c]));
        }
    };

    u32x4 gcur[8], gnxt[8];
    float wcur[4], wnxt[4];
    issue_g(0, gcur, wcur);

    f32x4 acc[4] = {};
#pragma unroll
    for (int k = 0; k < 9; ++k) {
        // full drain: tap-k's gathers are architecturally settled here
        asm volatile("s_waitcnt vmcnt(0)" ::: "memory");
        __builtin_amdgcn_sched_barrier(0);
        // issue next tap's gathers (in flight across blend+MFMA below)
        if (k < 8) issue_g(k + 1, gnxt, wnxt);
        // blend tap k in load mapping, shfl to MFMA mapping, MFMA
#pragma unroll
        for (int h = 0; h < 2; ++h) {
            bf16x8 afr[4];
#pragma unroll
            for (int mt = 0; mt < 4; ++mt)
                afr[mt] = *(const bf16x8*)
                    &wlds[(size_t)(((k * 2 + h) * 4 + lg) * 64 + mt * 16 + l15) * 8];
            union { unsigned u[4]; bf16x8 v; } bv;
#pragma unroll
            for (int qq = 0; qq < 4; ++qq) {   // qq-th u32 = 2 channels of my octet
                f32x2 s = {0.f, 0.f};
#pragma unroll
                for (int c = 0; c < 4; ++c) {
                    const unsigned u = gcur[h * 4 + c][qq];
                    f32x2 cf;
                    cf.x = __uint_as_float(u << 16);
                    cf.y = __uint_as_float(u & 0xffff0000u);
                    s.x = fmaf(wcur[c], cf.x, s.x);
                    s.y = fmaf(wcur[c], cf.y, s.y);
                }
                __hip_bfloat162 hh = __float22bfloat162_rn(make_float2(s.x, s.y));
                unsigned up; __builtin_memcpy(&up, &hh, 4);
                bv.u[qq] = (unsigned)__shfl((int)up, shfl_src);   // -> MFMA layout
            }
#pragma unroll
            for (int mt = 0; mt < 4; ++mt)
                acc[mt] = __builtin_amdgcn_mfma_f32_16x16x32_bf16(
                    afr[mt], bv.v, acc[mt], 0, 0, 0);
        }
        // rotate ping-pong (renamed away under full unroll; proven in r8/r11)
#pragma unroll
        for (int c = 0; c < 8; ++c) gcur[c] = gnxt[c];
#pragma unroll
        for (int c = 0; c < 4; ++c) wcur[c] = wnxt[c];
    }

#pragma unroll
    for (int mt = 0; mt < 4; ++mt)
#pragma unroll
        for (int j = 0; j < 4; ++j) {
            const int co = mt * 16 + lg * 4 + j;
            out[(((size_t)(b * CC + co)) * HH + y) * WW + xo] = acc[mt][j];
        }
}

// ---------------------------------------------------------------------------
// Workspace:
//   in_nhwc  bf16  33,554,432
//   est_nhwc bf16  33,554,432
//   offs     f32    9,437,184
//   wE2      bf16     294,912
//   wO2      bf16      73,728
//   wD4      bf16      73,728
//   zpage             256 (zeroed each launch)
// total ~77 MB
// ---------------------------------------------------------------------------
extern "C" void kernel_launch(void* const* d_in, const int* in_sizes, int n_in,
                              void* d_out, int out_size, void* d_ws, size_t ws_size,
                              hipStream_t stream) {
    const float* lr    = (const float*)d_in[0];
    const float* hr    = (const float*)d_in[1];
    const float* w_est = (const float*)d_in[2];
    const float* w_off = (const float*)d_in[3];
    const float* w_def = (const float*)d_in[4];
    float* out = (float*)d_out;

    char* ws = (char*)d_ws;
    ushort* in_nhwc  = (ushort*)ws;   ws += (size_t)BB * HH * WW * 128 * 2;
    ushort* est_nhwc = (ushort*)ws;   ws += (size_t)BB * HH * WW * 128 * 2;
    float*  offs     = (float*)ws;    ws += (size_t)BB * 18 * HW * 4;
    ushort* wE2      = (ushort*)ws;   ws += (size_t)128 * 1152 * 2;
    ushort* wO2      = (ushort*)ws;   ws += (size_t)144 * 32 * 8 * 2;
    ushort* wD4      = (ushort*)ws;   ws += (size_t)9 * 4096 * 2;
    ushort* zp       = (ushort*)ws;

    hipMemsetAsync(zp, 0, 256, stream);
    pack_wE2<<<(128 * 1152 + 255) / 256, 256, 0, stream>>>(w_est, wE2);
    pack_wO2<<<(144 * 32 * 8 + 255) / 256, 256, 0, stream>>>(w_off, wO2);
    pack_wD4<<<(9 * 4096 + 255) / 256, 256, 0, stream>>>(w_def, wD4);

    to_nhwc_bf16<<<BB * HH, 256, 0, stream>>>(lr, hr, in_nhwc);

    conv1_mfma<<<BB * (HH / 4), 512, 0, stream>>>(in_nhwc, wE2, zp, est_nhwc);
    conv2_mfma<<<BB * (HH / 4), 512, 0, stream>>>(est_nhwc, wO2, zp, offs);

    deform_mfma<<<BB * HH, 512, 0, stream>>>(in_nhwc, offs, wD4, out);
}